// Round 11
// baseline (878.332 us; speedup 1.0000x reference)
//
#include <hip/hip_runtime.h>
#include <hip/hip_bf16.h>

#define NN 50000
#define NNP 50048   // padded to 64-node blocks
#define NE 400000
#define FH 64

typedef __attribute__((ext_vector_type(8))) short short8;
typedef __attribute__((ext_vector_type(8))) _Float16 half8;
typedef __attribute__((ext_vector_type(4))) float float4v;

__device__ __forceinline__ float silu_f(float x) {
    return x * __builtin_amdgcn_rcpf(1.0f + __expf(-x));
}
__device__ __forceinline__ short f2h(float f) {
    _Float16 h = (_Float16)f;
    return *(short*)&h;
}
__device__ __forceinline__ float h2f(short s) {
    _Float16 h = *(_Float16*)&s;
    return (float)h;
}

// ---------------- mega weight prep (single fp16 frags) ----------------
__device__ __forceinline__ void frag_body(const float* __restrict__ src,
                                          short* __restrict__ dst,
                                          int t, int K, int N, int KT, int dup,
                                          int perL, int srcL) {
    int l = t / perL, tt = t - l * perL;
    int j = tt & 7, lane = (tt >> 3) & 63, frag = tt >> 9;
    int nt = frag / KT, kt = frag - nt * KT;
    int k = kt * 32 + ((lane >> 4) << 3) + j;
    int n = nt * 16 + (lane & 15);
    if (k == dup) k = dup - 1;
    float v = (k < K && n < N) ? src[(size_t)l * srcL + k * N + n] : 0.f;
    dst[t] = f2h(v);
}

__global__ void prep_all(const float* __restrict__ eW1, const float* __restrict__ eW2,
                         const float* __restrict__ cW1, const float* __restrict__ nW1,
                         const float* __restrict__ nW2, const float* __restrict__ eb1,
                         short* W1f, short* W2f, short* cW1f, short* nW1f,
                         short* nW2f, float* b1p) {
    int t = blockIdx.x * 256 + threadIdx.x;
    if (t < 130560) { frag_body(eW1, W1f, t, 131, 260, 5, 130, 43520, 33800); return; }
    t -= 130560;
    if (t < 55296) { frag_body(eW2, W2f, t, 260, 64, 9, -1, 18432, 16640); return; }
    t -= 55296;
    if (t < 49152) { frag_body(cW1, cW1f, t, 64, 256, 2, -1, 16384, 16384); return; }
    t -= 49152;
    if (t < 49152) { frag_body(nW1, nW1f, t, 128, 128, 4, -1, 16384, 16384); return; }
    t -= 49152;
    if (t < 24576) { frag_body(nW2, nW2f, t, 128, 64, 4, -1, 8192, 8192); return; }
    t -= 24576;
    if (t < 816) { int l = t / 272, c = t - l * 272; b1p[t] = (c < 260) ? eb1[l * 260 + c] : 0.f; }
}

__global__ void embed_kernel(const float* __restrict__ x, const float* __restrict__ W,
                             const float* __restrict__ b, const float* __restrict__ pos,
                             float* __restrict__ feats, short* __restrict__ featsh,
                             float* __restrict__ cA) {
    int t = blockIdx.x * 256 + threadIdx.x;
    if (t >= NN * FH) return;
    int n = t >> 6, hcol = t & 63;
    float acc = b[hcol];
    #pragma unroll
    for (int k = 0; k < 8; k++) acc += x[n * 8 + k] * W[k * FH + hcol];
    feats[t] = acc;
    featsh[t] = f2h(acc);
    if (hcol < 3) cA[n * 3 + hcol] = pos[n * 3 + hcol];
}

// ---------------- CSR build (block scan + global cursor) ----------------
__global__ void hist_kernel(const int* __restrict__ ei, int* __restrict__ deg) {
    int e = blockIdx.x * 256 + threadIdx.x;
    if (e >= NE) return;
    atomicAdd(&deg[ei[e]], 1);
}

__global__ void alloc_kernel(const int* __restrict__ deg, int* __restrict__ off,
                             int* __restrict__ cursor, int* __restrict__ gcount) {
    __shared__ int s[256];
    __shared__ int base;
    int t = threadIdx.x, n = blockIdx.x * 256 + t;
    int d = (n < NN) ? deg[n] : 0;
    s[t] = d;
    __syncthreads();
    for (int st = 1; st < 256; st <<= 1) {
        int v = (t >= st) ? s[t - st] : 0;
        __syncthreads();
        s[t] += v;
        __syncthreads();
    }
    if (t == 255) base = atomicAdd(gcount, s[255]);
    __syncthreads();
    if (n < NN) { int o = base + s[t] - d; off[n] = o; cursor[n] = o; }
}

__global__ void fill_kernel(const int* __restrict__ ei, const float* __restrict__ eattr,
                            int* __restrict__ cursor, int* __restrict__ erow,
                            int* __restrict__ ecol, float* __restrict__ eattrp) {
    int e = blockIdx.x * 256 + threadIdx.x;
    if (e >= NE) return;
    int r = ei[e];
    int p = atomicAdd(&cursor[r], 1);
    erow[p] = r;
    ecol[p] = ei[NE + e];
    eattrp[p] = eattr[e];
}

// ---------------- fused MFMA edge pipeline (fp16, 4 blocks/CU) ----------------
#define SE_STRIDE 168   // shorts
#define H1_STRIDE 296
#define M_STRIDE  72

__global__ __launch_bounds__(256, 4) void edge_fused(
    const int* __restrict__ erow, const int* __restrict__ ecol,
    const float* __restrict__ eattrp,
    const short* __restrict__ featsh, const float* __restrict__ coors,
    const short* __restrict__ W1f, const float* __restrict__ b1p,
    const short* __restrict__ W2f, const float* __restrict__ b2,
    const short* __restrict__ cW1f, const float* __restrict__ cb1,
    const float* __restrict__ cW2, const float* __restrict__ cb2,
    short* __restrict__ m_edge, float* __restrict__ cwrel)
{
    // 39680 B total -> 4 blocks/CU (4 x 39680 = 158720 <= 160 KiB)
    __shared__ char smem[39680];
    short* sE   = (short*)smem;               // [0,21504)   gather -> af load
    short* sH1  = (short*)smem;               // [0,37888)   GEMM1 out (overlays sE)
    short* sM   = (short*)smem;               // [0,9216)    m tile (overlays dead H1 after GEMM2)
    float* sRel = (float*)(smem + 37888);     // 768 B
    float* cwbuf = (float*)(smem + 38656);    // 1024 B

    int t = threadIdx.x;
    int k0 = blockIdx.x * 64;
    int lane = t & 63, wid = t >> 6, quad = lane >> 4, lc = lane & 15;

    // ---- phase 1: gather e_in ----
    {
        int el = t >> 2, sub = t & 3, k = k0 + el;
        int rI = erow[k], cI = ecol[k];
        const short8* fr = (const short8*)(featsh + (size_t)rI * FH);
        const short8* fc = (const short8*)(featsh + (size_t)cI * FH);
        short* er = sE + el * SE_STRIDE;
        *(short8*)(er + sub * 16) = fr[sub * 2];
        *(short8*)(er + sub * 16 + 8) = fr[sub * 2 + 1];
        *(short8*)(er + 64 + sub * 16) = fc[sub * 2];
        *(short8*)(er + 64 + sub * 16 + 8) = fc[sub * 2 + 1];
        #pragma unroll
        for (int i = 0; i < 10; i++) er[128 + sub * 10 + i] = 0;
        if (sub == 0) {
            float rx = coors[rI * 3 + 0] - coors[cI * 3 + 0];
            float ry = coors[rI * 3 + 1] - coors[cI * 3 + 1];
            float rz = coors[rI * 3 + 2] - coors[cI * 3 + 2];
            float dist = rx * rx + ry * ry + rz * rz;
            short dh = f2h(dist);
            er[128] = f2h(eattrp[k]);
            er[129] = dh;
            er[130] = f2h(dist - h2f(dh));   // dist hi/lo columns (W1 row 130 = dup of 129)
            sRel[el * 3 + 0] = rx; sRel[el * 3 + 1] = ry; sRel[el * 3 + 2] = rz;
        }
    }
    __syncthreads();

    // ---- phase 2: A fragments to registers, fence before overlay ----
    half8 af[4][5];
    #pragma unroll
    for (int m = 0; m < 4; m++)
        #pragma unroll
        for (int kt = 0; kt < 5; kt++)
            af[m][kt] = *(const half8*)(sE + (m * 16 + lc) * SE_STRIDE + kt * 32 + quad * 8);
    __syncthreads();

    // ---- phase 3: GEMM1 e_in[64x160] @ W1[160x272] -> silu -> sH1 ----
    {
        *(long long*)(sH1 + (t >> 2) * H1_STRIDE + 272 + (t & 3) * 4) = 0LL;
        #pragma unroll
        for (int i = 0; i < 4; i++) {
            int nt = wid + i * 4;
            float bias = b1p[nt * 16 + lc];
            float4v acc[4];
            #pragma unroll
            for (int m = 0; m < 4; m++) acc[m] = (float4v){bias, bias, bias, bias};
            #pragma unroll
            for (int kt = 0; kt < 5; kt++) {
                half8 bh = ((const half8*)(W1f + (size_t)(nt * 5 + kt) * 512))[lane];
                #pragma unroll
                for (int m = 0; m < 4; m++)
                    acc[m] = __builtin_amdgcn_mfma_f32_16x16x32_f16(af[m][kt], bh, acc[m], 0, 0, 0);
            }
            #pragma unroll
            for (int m = 0; m < 4; m++)
                #pragma unroll
                for (int r = 0; r < 4; r++)
                    sH1[(m * 16 + quad * 4 + r) * H1_STRIDE + nt * 16 + lc] = f2h(silu_f(acc[m][r]));
        }
        if (wid == 0) {
            const int nt = 16;
            float bias = b1p[nt * 16 + lc];
            float4v acc[4];
            #pragma unroll
            for (int m = 0; m < 4; m++) acc[m] = (float4v){bias, bias, bias, bias};
            #pragma unroll
            for (int kt = 0; kt < 5; kt++) {
                half8 bh = ((const half8*)(W1f + (size_t)(nt * 5 + kt) * 512))[lane];
                #pragma unroll
                for (int m = 0; m < 4; m++)
                    acc[m] = __builtin_amdgcn_mfma_f32_16x16x32_f16(af[m][kt], bh, acc[m], 0, 0, 0);
            }
            #pragma unroll
            for (int m = 0; m < 4; m++)
                #pragma unroll
                for (int r = 0; r < 4; r++)
                    sH1[(m * 16 + quad * 4 + r) * H1_STRIDE + nt * 16 + lc] = f2h(silu_f(acc[m][r]));
        }
    }
    __syncthreads();

    // ---- phase 4: GEMM2 H1[64x288] @ W2[288x64] -> regs ----
    float4v macc[4];
    {
        int nt = wid;
        float bias = b2[nt * 16 + lc];
        #pragma unroll
        for (int m = 0; m < 4; m++) macc[m] = (float4v){bias, bias, bias, bias};
        #pragma unroll
        for (int kt = 0; kt < 9; kt++) {
            half8 bh = ((const half8*)(W2f + (size_t)(nt * 9 + kt) * 512))[lane];
            #pragma unroll
            for (int m = 0; m < 4; m++) {
                half8 a = *(const half8*)(sH1 + (m * 16 + lc) * H1_STRIDE + kt * 32 + quad * 8);
                macc[m] = __builtin_amdgcn_mfma_f32_16x16x32_f16(a, bh, macc[m], 0, 0, 0);
            }
        }
    }
    __syncthreads();   // all H1 reads done -> sM may overlay H1 region

    // ---- phase 4b: silu(m) -> sM (overlaying dead H1) ----
    {
        int nt = wid;
        #pragma unroll
        for (int m = 0; m < 4; m++)
            #pragma unroll
            for (int r = 0; r < 4; r++)
                sM[(m * 16 + quad * 4 + r) * M_STRIDE + nt * 16 + lc] = f2h(silu_f(macc[m][r]));
    }
    __syncthreads();

    // ---- phase 5: m -> global + GEMM3 ----
    {
        int row = t >> 2, c0 = (t & 3) * 16;
        short8 v0 = *(const short8*)(sM + row * M_STRIDE + c0);
        short8 v1 = *(const short8*)(sM + row * M_STRIDE + c0 + 8);
        short* mg = m_edge + (size_t)(k0 + row) * FH + c0;
        *(short8*)(mg) = v0;
        *(short8*)(mg + 8) = v1;
    }
    {
        half8 ag[4][2];
        #pragma unroll
        for (int m = 0; m < 4; m++)
            #pragma unroll
            for (int kt = 0; kt < 2; kt++)
                ag[m][kt] = *(const half8*)(sM + (m * 16 + lc) * M_STRIDE + kt * 32 + quad * 8);
        float cwpart[4][4];
        #pragma unroll
        for (int m = 0; m < 4; m++)
            #pragma unroll
            for (int r = 0; r < 4; r++) cwpart[m][r] = 0.f;
        #pragma unroll
        for (int i = 0; i < 4; i++) {
            int nt = wid + i * 4;
            float bias = cb1[nt * 16 + lc];
            float4v acc[4];
            #pragma unroll
            for (int m = 0; m < 4; m++) acc[m] = (float4v){bias, bias, bias, bias};
            #pragma unroll
            for (int kt = 0; kt < 2; kt++) {
                half8 bh = ((const half8*)(cW1f + (size_t)(nt * 2 + kt) * 512))[lane];
                #pragma unroll
                for (int m = 0; m < 4; m++)
                    acc[m] = __builtin_amdgcn_mfma_f32_16x16x32_f16(ag[m][kt], bh, acc[m], 0, 0, 0);
            }
            float wv = cW2[nt * 16 + lc];
            #pragma unroll
            for (int m = 0; m < 4; m++)
                #pragma unroll
                for (int r = 0; r < 4; r++)
                    cwpart[m][r] += silu_f(acc[m][r]) * wv;
        }
        #pragma unroll
        for (int m = 0; m < 4; m++)
            #pragma unroll
            for (int r = 0; r < 4; r++) {
                float p = cwpart[m][r];
                p += __shfl_xor(p, 1);
                p += __shfl_xor(p, 2);
                p += __shfl_xor(p, 4);
                p += __shfl_xor(p, 8);
                if (lc == 0) cwbuf[wid * 64 + m * 16 + quad * 4 + r] = p;
            }
    }
    __syncthreads();

    if (t < 64) {
        float cw = cb2[0] + cwbuf[t] + cwbuf[64 + t] + cwbuf[128 + t] + cwbuf[192 + t];
        float* o = cwrel + (size_t)(k0 + t) * 3;
        o[0] = cw * sRel[t * 3 + 0];
        o[1] = cw * sRel[t * 3 + 1];
        o[2] = cw * sRel[t * 3 + 2];
    }
}

// ---------------- fused aggregation + node MLP (fp16, 4 blocks/CU) ----------------
#define HS 136
__global__ __launch_bounds__(256, 4) void agg_node(
    const int* __restrict__ off, const int* __restrict__ deg,
    const short* __restrict__ m_edge, const float* __restrict__ cwrel,
    const float* __restrict__ coors_in, float* __restrict__ coors_out,
    float* __restrict__ feats, short* __restrict__ featsh,
    const short* __restrict__ W1f, const float* __restrict__ b1,
    const short* __restrict__ W2f, const float* __restrict__ b2)
{
    __shared__ short sh[64 * HS];   // h = [featsh | agg(m)]
    __shared__ short sg[64 * HS];   // silu(h@W1+b1)
    int t = threadIdx.x, lane = t & 63, wid = t >> 6, quad = lane >> 4, lc = lane & 15;
    int n0 = blockIdx.x * 64;

    {
        int row = t >> 2, sub = t & 3;
        const short8* fp = (const short8*)(featsh + (size_t)(n0 + row) * FH);
        *(short8*)(sh + row * HS + sub * 16) = fp[sub * 2];
        *(short8*)(sh + row * HS + sub * 16 + 8) = fp[sub * 2 + 1];
    }
    for (int nn = 0; nn < 16; nn++) {
        int row = wid * 16 + nn;
        int n = n0 + row;
        float sum = 0.f, cv = 0.f;
        if (n < NN) {
            int s = off[n], e = s + deg[n];
            for (int k = s; k < e; k++) {
                sum += h2f(m_edge[(size_t)k * FH + lane]);
                if (lane < 3) cv += cwrel[(size_t)k * 3 + lane];
            }
            if (lane < 3) coors_out[n * 3 + lane] = coors_in[n * 3 + lane] + cv;
        }
        sh[row * HS + 64 + lane] = f2h(sum);
    }
    __syncthreads();

    half8 af[4][4];
    #pragma unroll
    for (int m = 0; m < 4; m++)
        #pragma unroll
        for (int kt = 0; kt < 4; kt++)
            af[m][kt] = *(const half8*)(sh + (m * 16 + lc) * HS + kt * 32 + quad * 8);
    #pragma unroll
    for (int i = 0; i < 2; i++) {
        int nt = wid + i * 4;
        float bias = b1[nt * 16 + lc];
        float4v acc[4];
        #pragma unroll
        for (int m = 0; m < 4; m++) acc[m] = (float4v){bias, bias, bias, bias};
        #pragma unroll
        for (int kt = 0; kt < 4; kt++) {
            half8 bh = ((const half8*)(W1f + (size_t)(nt * 4 + kt) * 512))[lane];
            #pragma unroll
            for (int m = 0; m < 4; m++)
                acc[m] = __builtin_amdgcn_mfma_f32_16x16x32_f16(af[m][kt], bh, acc[m], 0, 0, 0);
        }
        #pragma unroll
        for (int m = 0; m < 4; m++)
            #pragma unroll
            for (int r = 0; r < 4; r++)
                sg[(m * 16 + quad * 4 + r) * HS + nt * 16 + lc] = f2h(silu_f(acc[m][r]));
    }
    __syncthreads();

    {
        int nt = wid;
        float bias = b2[nt * 16 + lc];
        float4v acc[4];
        #pragma unroll
        for (int m = 0; m < 4; m++) acc[m] = (float4v){bias, bias, bias, bias};
        #pragma unroll
        for (int kt = 0; kt < 4; kt++) {
            half8 bh = ((const half8*)(W2f + (size_t)(nt * 4 + kt) * 512))[lane];
            #pragma unroll
            for (int m = 0; m < 4; m++) {
                half8 a = *(const half8*)(sg + (m * 16 + lc) * HS + kt * 32 + quad * 8);
                acc[m] = __builtin_amdgcn_mfma_f32_16x16x32_f16(a, bh, acc[m], 0, 0, 0);
            }
        }
        #pragma unroll
        for (int m = 0; m < 4; m++)
            #pragma unroll
            for (int r = 0; r < 4; r++) {
                int row = m * 16 + quad * 4 + r;
                size_t idx = (size_t)(n0 + row) * FH + nt * 16 + lc;
                float nv = feats[idx] + acc[m][r];   // residual in fp32
                feats[idx] = nv;
                featsh[idx] = f2h(nv);
            }
    }
}

__global__ void final_kernel(const float* __restrict__ feats, const float* __restrict__ linW,
                             const float* __restrict__ linb, float* __restrict__ out) {
    int t = blockIdx.x * 256 + threadIdx.x;
    int n = t >> 6;
    int lane = threadIdx.x & 63;
    if (n >= NN) return;
    float v = feats[(size_t)n * FH + lane] * linW[lane];
    #pragma unroll
    for (int off = 32; off > 0; off >>= 1) v += __shfl_down(v, off);
    if (lane == 0) out[n] = v + linb[0];
}

extern "C" void kernel_launch(void* const* d_in, const int* in_sizes, int n_in,
                              void* d_out, int out_size, void* d_ws, size_t ws_size,
                              hipStream_t stream) {
    const float* x      = (const float*)d_in[0];
    const float* pos    = (const float*)d_in[1];
    const int*   ei     = (const int*)d_in[2];
    const float* eattr  = (const float*)d_in[3];
    const float* embedW = (const float*)d_in[4];
    const float* embedb = (const float*)d_in[5];
    const float* eW1    = (const float*)d_in[6];
    const float* eb1    = (const float*)d_in[7];
    const float* eW2    = (const float*)d_in[8];
    const float* eb2    = (const float*)d_in[9];
    const float* cW1    = (const float*)d_in[10];
    const float* cb1    = (const float*)d_in[11];
    const float* cW2    = (const float*)d_in[12];
    const float* cb2    = (const float*)d_in[13];
    const float* nW1    = (const float*)d_in[14];
    const float* nb1    = (const float*)d_in[15];
    const float* nW2    = (const float*)d_in[16];
    const float* nb2    = (const float*)d_in[17];
    const float* linW   = (const float*)d_in[18];
    const float* linb   = (const float*)d_in[19];
    float* out = (float*)d_out;

    char* wp = (char*)d_ws;
    auto alloc = [&](size_t bytes) { void* p = wp; wp += (bytes + 255) & ~(size_t)255; return p; };

    const int W1F_L  = 17 * 5 * 512;
    const int W2F_L  = 4 * 9 * 512;
    const int CW1F_L = 16 * 2 * 512;
    const int NW1F_L = 8 * 4 * 512;
    const int NW2F_L = 4 * 4 * 512;

    float* feats  = (float*)alloc((size_t)NNP * FH * 4);
    short* featsh = (short*)alloc((size_t)NNP * FH * 2);
    float* cA     = (float*)alloc((size_t)NN * 3 * 4);
    float* cB     = (float*)alloc((size_t)NN * 3 * 4);
    short* W1f    = (short*)alloc((size_t)3 * W1F_L * 2);
    short* W2f    = (short*)alloc((size_t)3 * W2F_L * 2);
    short* cW1f   = (short*)alloc((size_t)3 * CW1F_L * 2);
    short* nW1f   = (short*)alloc((size_t)3 * NW1F_L * 2);
    short* nW2f   = (short*)alloc((size_t)3 * NW2F_L * 2);
    float* b1p    = (float*)alloc((size_t)3 * 272 * 4);
    int*   deg    = (int*)alloc((size_t)(NN + 1) * 4);   // deg[NN] = global cursor
    int*   off    = (int*)alloc((size_t)NN * 4);
    int*   cursor = (int*)alloc((size_t)NN * 4);
    int*   erow   = (int*)alloc((size_t)NE * 4);
    int*   ecol   = (int*)alloc((size_t)NE * 4);
    float* eattrp = (float*)alloc((size_t)NE * 4);
    short* m_edge = (short*)alloc((size_t)NE * FH * 2);
    float* cwrel  = (float*)alloc((size_t)NE * 3 * 4);
    int* gcount = deg + NN;

    prep_all<<<(309552 + 255) / 256, 256, 0, stream>>>(
        eW1, eW2, cW1, nW1, nW2, eb1,
        W1f, W2f, cW1f, nW1f, nW2f, b1p);

    hipMemsetAsync(deg, 0, (size_t)(NN + 1) * 4, stream);
    hist_kernel<<<(NE + 255) / 256, 256, 0, stream>>>(ei, deg);
    alloc_kernel<<<(NN + 255) / 256, 256, 0, stream>>>(deg, off, cursor, gcount);
    fill_kernel<<<(NE + 255) / 256, 256, 0, stream>>>(ei, eattr, cursor, erow, ecol, eattrp);

    embed_kernel<<<(NN * FH + 255) / 256, 256, 0, stream>>>(x, embedW, embedb, pos, feats, featsh, cA);

    float* ccur = cA;
    float* cnext = cB;
    for (int l = 0; l < 3; l++) {
        edge_fused<<<NE / 64, 256, 0, stream>>>(
            erow, ecol, eattrp, featsh, ccur,
            W1f + (size_t)l * W1F_L, b1p + l * 272,
            W2f + (size_t)l * W2F_L, eb2 + l * 64,
            cW1f + (size_t)l * CW1F_L, cb1 + l * 256,
            cW2 + l * 256, cb2 + l,
            m_edge, cwrel);
        agg_node<<<NNP / 64, 256, 0, stream>>>(
            off, deg, m_edge, cwrel, ccur, cnext, feats, featsh,
            nW1f + (size_t)l * NW1F_L, nb1 + l * 128,
            nW2f + (size_t)l * NW2F_L, nb2 + l * 64);
        float* tmp = ccur; ccur = cnext; cnext = tmp;
    }
    final_kernel<<<(NN * FH) / 256, 256, 0, stream>>>(feats, linW, linb, out);
}

// Round 12
// 866.971 us; speedup vs baseline: 1.0131x; 1.0131x over previous
//
#include <hip/hip_runtime.h>
#include <hip/hip_bf16.h>

#define NN 50000
#define NNP 50048   // padded to 64-node blocks
#define NE 400000
#define FH 64

typedef __attribute__((ext_vector_type(8))) short short8;
typedef __attribute__((ext_vector_type(8))) _Float16 half8;
typedef __attribute__((ext_vector_type(4))) float float4v;

__device__ __forceinline__ float silu_f(float x) {
    return x * __builtin_amdgcn_rcpf(1.0f + __expf(-x));
}
__device__ __forceinline__ short f2h(float f) {
    _Float16 h = (_Float16)f;
    return *(short*)&h;
}
__device__ __forceinline__ float h2f(short s) {
    _Float16 h = *(_Float16*)&s;
    return (float)h;
}

// ---------------- mega weight prep (single fp16 frags) ----------------
__device__ __forceinline__ void frag_body(const float* __restrict__ src,
                                          short* __restrict__ dst,
                                          int t, int K, int N, int KT, int dup,
                                          int perL, int srcL) {
    int l = t / perL, tt = t - l * perL;
    int j = tt & 7, lane = (tt >> 3) & 63, frag = tt >> 9;
    int nt = frag / KT, kt = frag - nt * KT;
    int k = kt * 32 + ((lane >> 4) << 3) + j;
    int n = nt * 16 + (lane & 15);
    if (k == dup) k = dup - 1;
    float v = (k < K && n < N) ? src[(size_t)l * srcL + k * N + n] : 0.f;
    dst[t] = f2h(v);
}

__global__ void prep_all(const float* __restrict__ eW1, const float* __restrict__ eW2,
                         const float* __restrict__ cW1, const float* __restrict__ nW1,
                         const float* __restrict__ nW2, const float* __restrict__ eb1,
                         short* W1f, short* W2f, short* cW1f, short* nW1f,
                         short* nW2f, float* b1p) {
    int t = blockIdx.x * 256 + threadIdx.x;
    if (t < 130560) { frag_body(eW1, W1f, t, 131, 260, 5, 130, 43520, 33800); return; }
    t -= 130560;
    if (t < 55296) { frag_body(eW2, W2f, t, 260, 64, 9, -1, 18432, 16640); return; }
    t -= 55296;
    if (t < 49152) { frag_body(cW1, cW1f, t, 64, 256, 2, -1, 16384, 16384); return; }
    t -= 49152;
    if (t < 49152) { frag_body(nW1, nW1f, t, 128, 128, 4, -1, 16384, 16384); return; }
    t -= 49152;
    if (t < 24576) { frag_body(nW2, nW2f, t, 128, 64, 4, -1, 8192, 8192); return; }
    t -= 24576;
    if (t < 816) { int l = t / 272, c = t - l * 272; b1p[t] = (c < 260) ? eb1[l * 260 + c] : 0.f; }
}

__global__ void embed_kernel(const float* __restrict__ x, const float* __restrict__ W,
                             const float* __restrict__ b, const float* __restrict__ pos,
                             float* __restrict__ feats, short* __restrict__ featsh,
                             float* __restrict__ cA) {
    int t = blockIdx.x * 256 + threadIdx.x;
    if (t >= NN * FH) return;
    int n = t >> 6, hcol = t & 63;
    float acc = b[hcol];
    #pragma unroll
    for (int k = 0; k < 8; k++) acc += x[n * 8 + k] * W[k * FH + hcol];
    feats[t] = acc;
    featsh[t] = f2h(acc);
    if (hcol < 3) cA[n * 3 + hcol] = pos[n * 3 + hcol];
}

// ---------------- CSR build (block scan + global cursor) ----------------
__global__ void hist_kernel(const int* __restrict__ ei, int* __restrict__ deg) {
    int e = blockIdx.x * 256 + threadIdx.x;
    if (e >= NE) return;
    atomicAdd(&deg[ei[e]], 1);
}

__global__ void alloc_kernel(const int* __restrict__ deg, int* __restrict__ off,
                             int* __restrict__ cursor, int* __restrict__ gcount) {
    __shared__ int s[256];
    __shared__ int base;
    int t = threadIdx.x, n = blockIdx.x * 256 + t;
    int d = (n < NN) ? deg[n] : 0;
    s[t] = d;
    __syncthreads();
    for (int st = 1; st < 256; st <<= 1) {
        int v = (t >= st) ? s[t - st] : 0;
        __syncthreads();
        s[t] += v;
        __syncthreads();
    }
    if (t == 255) base = atomicAdd(gcount, s[255]);
    __syncthreads();
    if (n < NN) { int o = base + s[t] - d; off[n] = o; cursor[n] = o; }
}

__global__ void fill_kernel(const int* __restrict__ ei, const float* __restrict__ eattr,
                            int* __restrict__ cursor, int* __restrict__ erow,
                            int* __restrict__ ecol, float* __restrict__ eattrp) {
    int e = blockIdx.x * 256 + threadIdx.x;
    if (e >= NE) return;
    int r = ei[e];
    int p = atomicAdd(&cursor[r], 1);
    erow[p] = r;
    ecol[p] = ei[NE + e];
    eattrp[p] = eattr[e];
}

// ---------------- fused MFMA edge pipeline (fp16) ----------------
// NOTE: 3 blocks/CU is the measured sweet spot — 4/CU (r11) thrashed per-XCD L2
// (FETCH 28.8->106 MB, WRITE 54.7->342 MB, edge 133->181 us). Streaming outputs
// use non-temporal stores to keep L2 free for featsh gathers + weight frags.
#define SE_STRIDE 168   // shorts
#define H1_STRIDE 296
#define M_STRIDE  72

__global__ __launch_bounds__(256, 3) void edge_fused(
    const int* __restrict__ erow, const int* __restrict__ ecol,
    const float* __restrict__ eattrp,
    const short* __restrict__ featsh, const float* __restrict__ coors,
    const short* __restrict__ W1f, const float* __restrict__ b1p,
    const short* __restrict__ W2f, const float* __restrict__ b2,
    const short* __restrict__ cW1f, const float* __restrict__ cb1,
    const float* __restrict__ cW2, const float* __restrict__ cb2,
    short* __restrict__ m_edge, float* __restrict__ cwrel)
{
    __shared__ char smem[39680];
    short* sE   = (short*)smem;               // [0,21504)   gather -> af load
    short* sH1  = (short*)smem;               // [0,37888)   GEMM1 out (overlays sE)
    short* sM   = (short*)smem;               // [0,9216)    m tile (overlays dead H1)
    float* sRel = (float*)(smem + 37888);     // 768 B
    float* cwbuf = (float*)(smem + 38656);    // 1024 B

    int t = threadIdx.x;
    int k0 = blockIdx.x * 64;
    int lane = t & 63, wid = t >> 6, quad = lane >> 4, lc = lane & 15;

    // ---- phase 1: gather e_in ----
    {
        int el = t >> 2, sub = t & 3, k = k0 + el;
        int rI = __builtin_nontemporal_load(erow + k);
        int cI = __builtin_nontemporal_load(ecol + k);
        const short8* fr = (const short8*)(featsh + (size_t)rI * FH);
        const short8* fc = (const short8*)(featsh + (size_t)cI * FH);
        short* er = sE + el * SE_STRIDE;
        *(short8*)(er + sub * 16) = fr[sub * 2];
        *(short8*)(er + sub * 16 + 8) = fr[sub * 2 + 1];
        *(short8*)(er + 64 + sub * 16) = fc[sub * 2];
        *(short8*)(er + 64 + sub * 16 + 8) = fc[sub * 2 + 1];
        #pragma unroll
        for (int i = 0; i < 10; i++) er[128 + sub * 10 + i] = 0;
        if (sub == 0) {
            float rx = coors[rI * 3 + 0] - coors[cI * 3 + 0];
            float ry = coors[rI * 3 + 1] - coors[cI * 3 + 1];
            float rz = coors[rI * 3 + 2] - coors[cI * 3 + 2];
            float dist = rx * rx + ry * ry + rz * rz;
            short dh = f2h(dist);
            er[128] = f2h(__builtin_nontemporal_load(eattrp + k));
            er[129] = dh;
            er[130] = f2h(dist - h2f(dh));   // dist hi/lo columns (W1 row 130 = dup of 129)
            sRel[el * 3 + 0] = rx; sRel[el * 3 + 1] = ry; sRel[el * 3 + 2] = rz;
        }
    }
    __syncthreads();

    // ---- phase 2: A fragments to registers, fence before overlay ----
    half8 af[4][5];
    #pragma unroll
    for (int m = 0; m < 4; m++)
        #pragma unroll
        for (int kt = 0; kt < 5; kt++)
            af[m][kt] = *(const half8*)(sE + (m * 16 + lc) * SE_STRIDE + kt * 32 + quad * 8);
    __syncthreads();

    // ---- phase 3: GEMM1 e_in[64x160] @ W1[160x272] -> silu -> sH1 ----
    {
        *(long long*)(sH1 + (t >> 2) * H1_STRIDE + 272 + (t & 3) * 4) = 0LL;
        #pragma unroll
        for (int i = 0; i < 4; i++) {
            int nt = wid + i * 4;
            float bias = b1p[nt * 16 + lc];
            float4v acc[4];
            #pragma unroll
            for (int m = 0; m < 4; m++) acc[m] = (float4v){bias, bias, bias, bias};
            #pragma unroll
            for (int kt = 0; kt < 5; kt++) {
                half8 bh = ((const half8*)(W1f + (size_t)(nt * 5 + kt) * 512))[lane];
                #pragma unroll
                for (int m = 0; m < 4; m++)
                    acc[m] = __builtin_amdgcn_mfma_f32_16x16x32_f16(af[m][kt], bh, acc[m], 0, 0, 0);
            }
            #pragma unroll
            for (int m = 0; m < 4; m++)
                #pragma unroll
                for (int r = 0; r < 4; r++)
                    sH1[(m * 16 + quad * 4 + r) * H1_STRIDE + nt * 16 + lc] = f2h(silu_f(acc[m][r]));
        }
        if (wid == 0) {
            const int nt = 16;
            float bias = b1p[nt * 16 + lc];
            float4v acc[4];
            #pragma unroll
            for (int m = 0; m < 4; m++) acc[m] = (float4v){bias, bias, bias, bias};
            #pragma unroll
            for (int kt = 0; kt < 5; kt++) {
                half8 bh = ((const half8*)(W1f + (size_t)(nt * 5 + kt) * 512))[lane];
                #pragma unroll
                for (int m = 0; m < 4; m++)
                    acc[m] = __builtin_amdgcn_mfma_f32_16x16x32_f16(af[m][kt], bh, acc[m], 0, 0, 0);
            }
            #pragma unroll
            for (int m = 0; m < 4; m++)
                #pragma unroll
                for (int r = 0; r < 4; r++)
                    sH1[(m * 16 + quad * 4 + r) * H1_STRIDE + nt * 16 + lc] = f2h(silu_f(acc[m][r]));
        }
    }
    __syncthreads();

    // ---- phase 4: GEMM2 H1[64x288] @ W2[288x64] -> regs ----
    float4v macc[4];
    {
        int nt = wid;
        float bias = b2[nt * 16 + lc];
        #pragma unroll
        for (int m = 0; m < 4; m++) macc[m] = (float4v){bias, bias, bias, bias};
        #pragma unroll
        for (int kt = 0; kt < 9; kt++) {
            half8 bh = ((const half8*)(W2f + (size_t)(nt * 9 + kt) * 512))[lane];
            #pragma unroll
            for (int m = 0; m < 4; m++) {
                half8 a = *(const half8*)(sH1 + (m * 16 + lc) * H1_STRIDE + kt * 32 + quad * 8);
                macc[m] = __builtin_amdgcn_mfma_f32_16x16x32_f16(a, bh, macc[m], 0, 0, 0);
            }
        }
    }
    __syncthreads();   // all H1 reads done -> sM may overlay H1 region

    // ---- phase 4b: silu(m) -> sM ----
    {
        int nt = wid;
        #pragma unroll
        for (int m = 0; m < 4; m++)
            #pragma unroll
            for (int r = 0; r < 4; r++)
                sM[(m * 16 + quad * 4 + r) * M_STRIDE + nt * 16 + lc] = f2h(silu_f(macc[m][r]));
    }
    __syncthreads();

    // ---- phase 5: m -> global (non-temporal) + GEMM3 ----
    {
        int row = t >> 2, c0 = (t & 3) * 16;
        short8 v0 = *(const short8*)(sM + row * M_STRIDE + c0);
        short8 v1 = *(const short8*)(sM + row * M_STRIDE + c0 + 8);
        short8* mg = (short8*)(m_edge + (size_t)(k0 + row) * FH + c0);
        __builtin_nontemporal_store(v0, mg);
        __builtin_nontemporal_store(v1, mg + 1);
    }
    {
        half8 ag[4][2];
        #pragma unroll
        for (int m = 0; m < 4; m++)
            #pragma unroll
            for (int kt = 0; kt < 2; kt++)
                ag[m][kt] = *(const half8*)(sM + (m * 16 + lc) * M_STRIDE + kt * 32 + quad * 8);
        float cwpart[4][4];
        #pragma unroll
        for (int m = 0; m < 4; m++)
            #pragma unroll
            for (int r = 0; r < 4; r++) cwpart[m][r] = 0.f;
        #pragma unroll
        for (int i = 0; i < 4; i++) {
            int nt = wid + i * 4;
            float bias = cb1[nt * 16 + lc];
            float4v acc[4];
            #pragma unroll
            for (int m = 0; m < 4; m++) acc[m] = (float4v){bias, bias, bias, bias};
            #pragma unroll
            for (int kt = 0; kt < 2; kt++) {
                half8 bh = ((const half8*)(cW1f + (size_t)(nt * 2 + kt) * 512))[lane];
                #pragma unroll
                for (int m = 0; m < 4; m++)
                    acc[m] = __builtin_amdgcn_mfma_f32_16x16x32_f16(ag[m][kt], bh, acc[m], 0, 0, 0);
            }
            float wv = cW2[nt * 16 + lc];
            #pragma unroll
            for (int m = 0; m < 4; m++)
                #pragma unroll
                for (int r = 0; r < 4; r++)
                    cwpart[m][r] += silu_f(acc[m][r]) * wv;
        }
        #pragma unroll
        for (int m = 0; m < 4; m++)
            #pragma unroll
            for (int r = 0; r < 4; r++) {
                float p = cwpart[m][r];
                p += __shfl_xor(p, 1);
                p += __shfl_xor(p, 2);
                p += __shfl_xor(p, 4);
                p += __shfl_xor(p, 8);
                if (lc == 0) cwbuf[wid * 64 + m * 16 + quad * 4 + r] = p;
            }
    }
    __syncthreads();

    if (t < 64) {
        float cw = cb2[0] + cwbuf[t] + cwbuf[64 + t] + cwbuf[128 + t] + cwbuf[192 + t];
        float* o = cwrel + (size_t)(k0 + t) * 3;
        __builtin_nontemporal_store(cw * sRel[t * 3 + 0], o + 0);
        __builtin_nontemporal_store(cw * sRel[t * 3 + 1], o + 1);
        __builtin_nontemporal_store(cw * sRel[t * 3 + 2], o + 2);
    }
}

// ---------------- fused aggregation + node MLP (fp16, 4 blocks/CU) ----------------
#define HS 136
__global__ __launch_bounds__(256, 4) void agg_node(
    const int* __restrict__ off, const int* __restrict__ deg,
    const short* __restrict__ m_edge, const float* __restrict__ cwrel,
    const float* __restrict__ coors_in, float* __restrict__ coors_out,
    float* __restrict__ feats, short* __restrict__ featsh,
    const short* __restrict__ W1f, const float* __restrict__ b1,
    const short* __restrict__ W2f, const float* __restrict__ b2)
{
    __shared__ short sh[64 * HS];   // h = [featsh | agg(m)]
    __shared__ short sg[64 * HS];   // silu(h@W1+b1)
    int t = threadIdx.x, lane = t & 63, wid = t >> 6, quad = lane >> 4, lc = lane & 15;
    int n0 = blockIdx.x * 64;

    {
        int row = t >> 2, sub = t & 3;
        const short8* fp = (const short8*)(featsh + (size_t)(n0 + row) * FH);
        *(short8*)(sh + row * HS + sub * 16) = fp[sub * 2];
        *(short8*)(sh + row * HS + sub * 16 + 8) = fp[sub * 2 + 1];
    }
    for (int nn = 0; nn < 16; nn++) {
        int row = wid * 16 + nn;
        int n = n0 + row;
        float sum = 0.f, cv = 0.f;
        if (n < NN) {
            int s = off[n], e = s + deg[n];
            for (int k = s; k < e; k++) {
                sum += h2f(__builtin_nontemporal_load(m_edge + (size_t)k * FH + lane));
                if (lane < 3) cv += __builtin_nontemporal_load(cwrel + (size_t)k * 3 + lane);
            }
            if (lane < 3) coors_out[n * 3 + lane] = coors_in[n * 3 + lane] + cv;
        }
        sh[row * HS + 64 + lane] = f2h(sum);
    }
    __syncthreads();

    half8 af[4][4];
    #pragma unroll
    for (int m = 0; m < 4; m++)
        #pragma unroll
        for (int kt = 0; kt < 4; kt++)
            af[m][kt] = *(const half8*)(sh + (m * 16 + lc) * HS + kt * 32 + quad * 8);
    #pragma unroll
    for (int i = 0; i < 2; i++) {
        int nt = wid + i * 4;
        float bias = b1[nt * 16 + lc];
        float4v acc[4];
        #pragma unroll
        for (int m = 0; m < 4; m++) acc[m] = (float4v){bias, bias, bias, bias};
        #pragma unroll
        for (int kt = 0; kt < 4; kt++) {
            half8 bh = ((const half8*)(W1f + (size_t)(nt * 4 + kt) * 512))[lane];
            #pragma unroll
            for (int m = 0; m < 4; m++)
                acc[m] = __builtin_amdgcn_mfma_f32_16x16x32_f16(af[m][kt], bh, acc[m], 0, 0, 0);
        }
        #pragma unroll
        for (int m = 0; m < 4; m++)
            #pragma unroll
            for (int r = 0; r < 4; r++)
                sg[(m * 16 + quad * 4 + r) * HS + nt * 16 + lc] = f2h(silu_f(acc[m][r]));
    }
    __syncthreads();

    {
        int nt = wid;
        float bias = b2[nt * 16 + lc];
        float4v acc[4];
        #pragma unroll
        for (int m = 0; m < 4; m++) acc[m] = (float4v){bias, bias, bias, bias};
        #pragma unroll
        for (int kt = 0; kt < 4; kt++) {
            half8 bh = ((const half8*)(W2f + (size_t)(nt * 4 + kt) * 512))[lane];
            #pragma unroll
            for (int m = 0; m < 4; m++) {
                half8 a = *(const half8*)(sg + (m * 16 + lc) * HS + kt * 32 + quad * 8);
                acc[m] = __builtin_amdgcn_mfma_f32_16x16x32_f16(a, bh, acc[m], 0, 0, 0);
            }
        }
        #pragma unroll
        for (int m = 0; m < 4; m++)
            #pragma unroll
            for (int r = 0; r < 4; r++) {
                int row = m * 16 + quad * 4 + r;
                size_t idx = (size_t)(n0 + row) * FH + nt * 16 + lc;
                float nv = feats[idx] + acc[m][r];   // residual in fp32
                feats[idx] = nv;
                featsh[idx] = f2h(nv);
            }
    }
}

__global__ void final_kernel(const float* __restrict__ feats, const float* __restrict__ linW,
                             const float* __restrict__ linb, float* __restrict__ out) {
    int t = blockIdx.x * 256 + threadIdx.x;
    int n = t >> 6;
    int lane = threadIdx.x & 63;
    if (n >= NN) return;
    float v = feats[(size_t)n * FH + lane] * linW[lane];
    #pragma unroll
    for (int off = 32; off > 0; off >>= 1) v += __shfl_down(v, off);
    if (lane == 0) out[n] = v + linb[0];
}

extern "C" void kernel_launch(void* const* d_in, const int* in_sizes, int n_in,
                              void* d_out, int out_size, void* d_ws, size_t ws_size,
                              hipStream_t stream) {
    const float* x      = (const float*)d_in[0];
    const float* pos    = (const float*)d_in[1];
    const int*   ei     = (const int*)d_in[2];
    const float* eattr  = (const float*)d_in[3];
    const float* embedW = (const float*)d_in[4];
    const float* embedb = (const float*)d_in[5];
    const float* eW1    = (const float*)d_in[6];
    const float* eb1    = (const float*)d_in[7];
    const float* eW2    = (const float*)d_in[8];
    const float* eb2    = (const float*)d_in[9];
    const float* cW1    = (const float*)d_in[10];
    const float* cb1    = (const float*)d_in[11];
    const float* cW2    = (const float*)d_in[12];
    const float* cb2    = (const float*)d_in[13];
    const float* nW1    = (const float*)d_in[14];
    const float* nb1    = (const float*)d_in[15];
    const float* nW2    = (const float*)d_in[16];
    const float* nb2    = (const float*)d_in[17];
    const float* linW   = (const float*)d_in[18];
    const float* linb   = (const float*)d_in[19];
    float* out = (float*)d_out;

    char* wp = (char*)d_ws;
    auto alloc = [&](size_t bytes) { void* p = wp; wp += (bytes + 255) & ~(size_t)255; return p; };

    const int W1F_L  = 17 * 5 * 512;
    const int W2F_L  = 4 * 9 * 512;
    const int CW1F_L = 16 * 2 * 512;
    const int NW1F_L = 8 * 4 * 512;
    const int NW2F_L = 4 * 4 * 512;

    float* feats  = (float*)alloc((size_t)NNP * FH * 4);
    short* featsh = (short*)alloc((size_t)NNP * FH * 2);
    float* cA     = (float*)alloc((size_t)NN * 3 * 4);
    float* cB     = (float*)alloc((size_t)NN * 3 * 4);
    short* W1f    = (short*)alloc((size_t)3 * W1F_L * 2);
    short* W2f    = (short*)alloc((size_t)3 * W2F_L * 2);
    short* cW1f   = (short*)alloc((size_t)3 * CW1F_L * 2);
    short* nW1f   = (short*)alloc((size_t)3 * NW1F_L * 2);
    short* nW2f   = (short*)alloc((size_t)3 * NW2F_L * 2);
    float* b1p    = (float*)alloc((size_t)3 * 272 * 4);
    int*   deg    = (int*)alloc((size_t)(NN + 1) * 4);   // deg[NN] = global cursor
    int*   off    = (int*)alloc((size_t)NN * 4);
    int*   cursor = (int*)alloc((size_t)NN * 4);
    int*   erow   = (int*)alloc((size_t)NE * 4);
    int*   ecol   = (int*)alloc((size_t)NE * 4);
    float* eattrp = (float*)alloc((size_t)NE * 4);
    short* m_edge = (short*)alloc((size_t)NE * FH * 2);
    float* cwrel  = (float*)alloc((size_t)NE * 3 * 4);
    int* gcount = deg + NN;

    prep_all<<<(309552 + 255) / 256, 256, 0, stream>>>(
        eW1, eW2, cW1, nW1, nW2, eb1,
        W1f, W2f, cW1f, nW1f, nW2f, b1p);

    hipMemsetAsync(deg, 0, (size_t)(NN + 1) * 4, stream);
    hist_kernel<<<(NE + 255) / 256, 256, 0, stream>>>(ei, deg);
    alloc_kernel<<<(NN + 255) / 256, 256, 0, stream>>>(deg, off, cursor, gcount);
    fill_kernel<<<(NE + 255) / 256, 256, 0, stream>>>(ei, eattr, cursor, erow, ecol, eattrp);

    embed_kernel<<<(NN * FH + 255) / 256, 256, 0, stream>>>(x, embedW, embedb, pos, feats, featsh, cA);

    float* ccur = cA;
    float* cnext = cB;
    for (int l = 0; l < 3; l++) {
        edge_fused<<<NE / 64, 256, 0, stream>>>(
            erow, ecol, eattrp, featsh, ccur,
            W1f + (size_t)l * W1F_L, b1p + l * 272,
            W2f + (size_t)l * W2F_L, eb2 + l * 64,
            cW1f + (size_t)l * CW1F_L, cb1 + l * 256,
            cW2 + l * 256, cb2 + l,
            m_edge, cwrel);
        agg_node<<<NNP / 64, 256, 0, stream>>>(
            off, deg, m_edge, cwrel, ccur, cnext, feats, featsh,
            nW1f + (size_t)l * NW1F_L, nb1 + l * 128,
            nW2f + (size_t)l * NW2F_L, nb2 + l * 64);
        float* tmp = ccur; ccur = cnext; cnext = tmp;
    }
    final_kernel<<<(NN * FH) / 256, 256, 0, stream>>>(feats, linW, linb, out);
}

// Round 13
// 659.588 us; speedup vs baseline: 1.3316x; 1.3144x over previous
//
#include <hip/hip_runtime.h>
#include <hip/hip_bf16.h>

#define NN 50000
#define NNP 50048   // padded to 64-node blocks
#define NE 400000
#define FH 64

typedef __attribute__((ext_vector_type(8))) short short8;
typedef __attribute__((ext_vector_type(8))) _Float16 half8;
typedef __attribute__((ext_vector_type(4))) float float4v;

__device__ __forceinline__ float silu_f(float x) {
    return x * __builtin_amdgcn_rcpf(1.0f + __expf(-x));
}
__device__ __forceinline__ short f2h(float f) {
    _Float16 h = (_Float16)f;
    return *(short*)&h;
}
__device__ __forceinline__ float h2f(short s) {
    _Float16 h = *(_Float16*)&s;
    return (float)h;
}

// ---------------- mega weight prep (single fp16 frags) ----------------
__device__ __forceinline__ void frag_body(const float* __restrict__ src,
                                          short* __restrict__ dst,
                                          int t, int K, int N, int KT, int dup,
                                          int perL, int srcL) {
    int l = t / perL, tt = t - l * perL;
    int j = tt & 7, lane = (tt >> 3) & 63, frag = tt >> 9;
    int nt = frag / KT, kt = frag - nt * KT;
    int k = kt * 32 + ((lane >> 4) << 3) + j;
    int n = nt * 16 + (lane & 15);
    if (k == dup) k = dup - 1;
    float v = (k < K && n < N) ? src[(size_t)l * srcL + k * N + n] : 0.f;
    dst[t] = f2h(v);
}

__global__ void prep_all(const float* __restrict__ eW1, const float* __restrict__ eW2,
                         const float* __restrict__ cW1, const float* __restrict__ nW1,
                         const float* __restrict__ nW2, const float* __restrict__ eb1,
                         short* W1f, short* W2f, short* cW1f, short* nW1f,
                         short* nW2f, float* b1p) {
    int t = blockIdx.x * 256 + threadIdx.x;
    if (t < 130560) { frag_body(eW1, W1f, t, 131, 260, 5, 130, 43520, 33800); return; }
    t -= 130560;
    if (t < 55296) { frag_body(eW2, W2f, t, 260, 64, 9, -1, 18432, 16640); return; }
    t -= 55296;
    if (t < 49152) { frag_body(cW1, cW1f, t, 64, 256, 2, -1, 16384, 16384); return; }
    t -= 49152;
    if (t < 49152) { frag_body(nW1, nW1f, t, 128, 128, 4, -1, 16384, 16384); return; }
    t -= 49152;
    if (t < 24576) { frag_body(nW2, nW2f, t, 128, 64, 4, -1, 8192, 8192); return; }
    t -= 24576;
    if (t < 816) { int l = t / 272, c = t - l * 272; b1p[t] = (c < 260) ? eb1[l * 260 + c] : 0.f; }
}

__global__ void embed_kernel(const float* __restrict__ x, const float* __restrict__ W,
                             const float* __restrict__ b, const float* __restrict__ pos,
                             float* __restrict__ feats, short* __restrict__ featsh,
                             float* __restrict__ cA) {
    int t = blockIdx.x * 256 + threadIdx.x;
    if (t >= NN * FH) return;
    int n = t >> 6, hcol = t & 63;
    float acc = b[hcol];
    #pragma unroll
    for (int k = 0; k < 8; k++) acc += x[n * 8 + k] * W[k * FH + hcol];
    feats[t] = acc;
    featsh[t] = f2h(acc);
    if (hcol < 3) cA[n * 3 + hcol] = pos[n * 3 + hcol];
}

// ---------------- CSR build (block scan + global cursor) ----------------
__global__ void hist_kernel(const int* __restrict__ ei, int* __restrict__ deg) {
    int e = blockIdx.x * 256 + threadIdx.x;
    if (e >= NE) return;
    atomicAdd(&deg[ei[e]], 1);
}

__global__ void alloc_kernel(const int* __restrict__ deg, int* __restrict__ off,
                             int* __restrict__ cursor, int* __restrict__ gcount) {
    __shared__ int s[256];
    __shared__ int base;
    int t = threadIdx.x, n = blockIdx.x * 256 + t;
    int d = (n < NN) ? deg[n] : 0;
    s[t] = d;
    __syncthreads();
    for (int st = 1; st < 256; st <<= 1) {
        int v = (t >= st) ? s[t - st] : 0;
        __syncthreads();
        s[t] += v;
        __syncthreads();
    }
    if (t == 255) base = atomicAdd(gcount, s[255]);
    __syncthreads();
    if (n < NN) { int o = base + s[t] - d; off[n] = o; cursor[n] = o; }
}

__global__ void fill_kernel(const int* __restrict__ ei, const float* __restrict__ eattr,
                            int* __restrict__ cursor, int* __restrict__ erow,
                            int* __restrict__ ecol, float* __restrict__ eattrp) {
    int e = blockIdx.x * 256 + threadIdx.x;
    if (e >= NE) return;
    int r = ei[e];
    int p = atomicAdd(&cursor[r], 1);
    erow[p] = r;
    ecol[p] = ei[NE + e];
    eattrp[p] = eattr[e];
}

// ---------------- fused MFMA edge pipeline (fp16, r10-proven structure) ----------------
// NOTE: 3 blocks/CU is the measured sweet spot — 4/CU (r11) thrashed per-XCD L2
// (FETCH 28.8->106 MB, edge 133->181 us). Non-temporal hints (r12) also regressed
// (edge 159 us; they defeat cross-layer erow/ecol L2 reuse + m_edge L2 handoff).
#define SE_STRIDE 168   // shorts
#define H1_STRIDE 296
#define M_STRIDE  72

__global__ __launch_bounds__(256, 3) void edge_fused(
    const int* __restrict__ erow, const int* __restrict__ ecol,
    const float* __restrict__ eattrp,
    const short* __restrict__ featsh, const float* __restrict__ coors,
    const short* __restrict__ W1f, const float* __restrict__ b1p,
    const short* __restrict__ W2f, const float* __restrict__ b2,
    const short* __restrict__ cW1f, const float* __restrict__ cb1,
    const float* __restrict__ cW2, const float* __restrict__ cb2,
    short* __restrict__ m_edge, float* __restrict__ cwrel)
{
    __shared__ char smem[48896];
    short* sE   = (short*)smem;               // [0,21504)
    short* sH1  = (short*)smem;               // [0,37888) overlays sE
    short* sM   = (short*)(smem + 37888);     // [37888,47104)
    float* sRel = (float*)(smem + 47104);
    float* cwbuf = (float*)(smem + 47872);

    int t = threadIdx.x;
    int k0 = blockIdx.x * 64;
    int lane = t & 63, wid = t >> 6, quad = lane >> 4, lc = lane & 15;

    // ---- phase 1: gather e_in ----
    {
        int el = t >> 2, sub = t & 3, k = k0 + el;
        int rI = erow[k], cI = ecol[k];
        const short8* fr = (const short8*)(featsh + (size_t)rI * FH);
        const short8* fc = (const short8*)(featsh + (size_t)cI * FH);
        short* er = sE + el * SE_STRIDE;
        *(short8*)(er + sub * 16) = fr[sub * 2];
        *(short8*)(er + sub * 16 + 8) = fr[sub * 2 + 1];
        *(short8*)(er + 64 + sub * 16) = fc[sub * 2];
        *(short8*)(er + 64 + sub * 16 + 8) = fc[sub * 2 + 1];
        #pragma unroll
        for (int i = 0; i < 10; i++) er[128 + sub * 10 + i] = 0;
        if (sub == 0) {
            float rx = coors[rI * 3 + 0] - coors[cI * 3 + 0];
            float ry = coors[rI * 3 + 1] - coors[cI * 3 + 1];
            float rz = coors[rI * 3 + 2] - coors[cI * 3 + 2];
            float dist = rx * rx + ry * ry + rz * rz;
            short dh = f2h(dist);
            er[128] = f2h(eattrp[k]);
            er[129] = dh;
            er[130] = f2h(dist - h2f(dh));   // dist hi/lo columns (W1 row 130 = dup of 129)
            sRel[el * 3 + 0] = rx; sRel[el * 3 + 1] = ry; sRel[el * 3 + 2] = rz;
        }
    }
    __syncthreads();

    // ---- phase 2: A fragments to registers, fence before overlay ----
    half8 af[4][5];
    #pragma unroll
    for (int m = 0; m < 4; m++)
        #pragma unroll
        for (int kt = 0; kt < 5; kt++)
            af[m][kt] = *(const half8*)(sE + (m * 16 + lc) * SE_STRIDE + kt * 32 + quad * 8);
    __syncthreads();

    // ---- phase 3: GEMM1 e_in[64x160] @ W1[160x272] -> silu -> sH1 ----
    {
        *(long long*)(sH1 + (t >> 2) * H1_STRIDE + 272 + (t & 3) * 4) = 0LL;
        #pragma unroll
        for (int i = 0; i < 4; i++) {
            int nt = wid + i * 4;
            float bias = b1p[nt * 16 + lc];
            float4v acc[4];
            #pragma unroll
            for (int m = 0; m < 4; m++) acc[m] = (float4v){bias, bias, bias, bias};
            #pragma unroll
            for (int kt = 0; kt < 5; kt++) {
                half8 bh = ((const half8*)(W1f + (size_t)(nt * 5 + kt) * 512))[lane];
                #pragma unroll
                for (int m = 0; m < 4; m++)
                    acc[m] = __builtin_amdgcn_mfma_f32_16x16x32_f16(af[m][kt], bh, acc[m], 0, 0, 0);
            }
            #pragma unroll
            for (int m = 0; m < 4; m++)
                #pragma unroll
                for (int r = 0; r < 4; r++)
                    sH1[(m * 16 + quad * 4 + r) * H1_STRIDE + nt * 16 + lc] = f2h(silu_f(acc[m][r]));
        }
        if (wid == 0) {
            const int nt = 16;
            float bias = b1p[nt * 16 + lc];
            float4v acc[4];
            #pragma unroll
            for (int m = 0; m < 4; m++) acc[m] = (float4v){bias, bias, bias, bias};
            #pragma unroll
            for (int kt = 0; kt < 5; kt++) {
                half8 bh = ((const half8*)(W1f + (size_t)(nt * 5 + kt) * 512))[lane];
                #pragma unroll
                for (int m = 0; m < 4; m++)
                    acc[m] = __builtin_amdgcn_mfma_f32_16x16x32_f16(af[m][kt], bh, acc[m], 0, 0, 0);
            }
            #pragma unroll
            for (int m = 0; m < 4; m++)
                #pragma unroll
                for (int r = 0; r < 4; r++)
                    sH1[(m * 16 + quad * 4 + r) * H1_STRIDE + nt * 16 + lc] = f2h(silu_f(acc[m][r]));
        }
    }
    __syncthreads();

    // ---- phase 4: GEMM2 H1[64x288] @ W2[288x64] -> silu -> sM ----
    {
        int nt = wid;
        float bias = b2[nt * 16 + lc];
        float4v acc[4];
        #pragma unroll
        for (int m = 0; m < 4; m++) acc[m] = (float4v){bias, bias, bias, bias};
        #pragma unroll
        for (int kt = 0; kt < 9; kt++) {
            half8 bh = ((const half8*)(W2f + (size_t)(nt * 9 + kt) * 512))[lane];
            #pragma unroll
            for (int m = 0; m < 4; m++) {
                half8 a = *(const half8*)(sH1 + (m * 16 + lc) * H1_STRIDE + kt * 32 + quad * 8);
                acc[m] = __builtin_amdgcn_mfma_f32_16x16x32_f16(a, bh, acc[m], 0, 0, 0);
            }
        }
        #pragma unroll
        for (int m = 0; m < 4; m++)
            #pragma unroll
            for (int r = 0; r < 4; r++)
                sM[(m * 16 + quad * 4 + r) * M_STRIDE + nt * 16 + lc] = f2h(silu_f(acc[m][r]));
    }
    __syncthreads();

    // ---- phase 5: m -> global + GEMM3 ----
    {
        int row = t >> 2, c0 = (t & 3) * 16;
        short8 v0 = *(const short8*)(sM + row * M_STRIDE + c0);
        short8 v1 = *(const short8*)(sM + row * M_STRIDE + c0 + 8);
        short* mg = m_edge + (size_t)(k0 + row) * FH + c0;
        *(short8*)(mg) = v0;
        *(short8*)(mg + 8) = v1;
    }
    {
        half8 ag[4][2];
        #pragma unroll
        for (int m = 0; m < 4; m++)
            #pragma unroll
            for (int kt = 0; kt < 2; kt++)
                ag[m][kt] = *(const half8*)(sM + (m * 16 + lc) * M_STRIDE + kt * 32 + quad * 8);
        float cwpart[4][4];
        #pragma unroll
        for (int m = 0; m < 4; m++)
            #pragma unroll
            for (int r = 0; r < 4; r++) cwpart[m][r] = 0.f;
        #pragma unroll
        for (int i = 0; i < 4; i++) {
            int nt = wid + i * 4;
            float bias = cb1[nt * 16 + lc];
            float4v acc[4];
            #pragma unroll
            for (int m = 0; m < 4; m++) acc[m] = (float4v){bias, bias, bias, bias};
            #pragma unroll
            for (int kt = 0; kt < 2; kt++) {
                half8 bh = ((const half8*)(cW1f + (size_t)(nt * 2 + kt) * 512))[lane];
                #pragma unroll
                for (int m = 0; m < 4; m++)
                    acc[m] = __builtin_amdgcn_mfma_f32_16x16x32_f16(ag[m][kt], bh, acc[m], 0, 0, 0);
            }
            float wv = cW2[nt * 16 + lc];
            #pragma unroll
            for (int m = 0; m < 4; m++)
                #pragma unroll
                for (int r = 0; r < 4; r++)
                    cwpart[m][r] += silu_f(acc[m][r]) * wv;
        }
        #pragma unroll
        for (int m = 0; m < 4; m++)
            #pragma unroll
            for (int r = 0; r < 4; r++) {
                float p = cwpart[m][r];
                p += __shfl_xor(p, 1);
                p += __shfl_xor(p, 2);
                p += __shfl_xor(p, 4);
                p += __shfl_xor(p, 8);
                if (lc == 0) cwbuf[wid * 64 + m * 16 + quad * 4 + r] = p;
            }
    }
    __syncthreads();

    if (t < 64) {
        float cw = cb2[0] + cwbuf[t] + cwbuf[64 + t] + cwbuf[128 + t] + cwbuf[192 + t];
        float* o = cwrel + (size_t)(k0 + t) * 3;
        o[0] = cw * sRel[t * 3 + 0];
        o[1] = cw * sRel[t * 3 + 1];
        o[2] = cw * sRel[t * 3 + 2];
    }
}

// ---------------- fused aggregation + node MLP (fp16) ----------------
#define HS 136
__global__ __launch_bounds__(256, 2) void agg_node(
    const int* __restrict__ off, const int* __restrict__ deg,
    const short* __restrict__ m_edge, const float* __restrict__ cwrel,
    const float* __restrict__ coors_in, float* __restrict__ coors_out,
    float* __restrict__ feats, short* __restrict__ featsh,
    const short* __restrict__ W1f, const float* __restrict__ b1,
    const short* __restrict__ W2f, const float* __restrict__ b2)
{
    __shared__ short sh[64 * HS];   // h = [featsh | agg(m)]
    __shared__ short sg[64 * HS];   // silu(h@W1+b1)
    int t = threadIdx.x, lane = t & 63, wid = t >> 6, quad = lane >> 4, lc = lane & 15;
    int n0 = blockIdx.x * 64;

    {
        int row = t >> 2, sub = t & 3;
        const short8* fp = (const short8*)(featsh + (size_t)(n0 + row) * FH);
        *(short8*)(sh + row * HS + sub * 16) = fp[sub * 2];
        *(short8*)(sh + row * HS + sub * 16 + 8) = fp[sub * 2 + 1];
    }
    // k-loop unrolled x2 with dual accumulators to overlap L2 load latency
    for (int nn = 0; nn < 16; nn++) {
        int row = wid * 16 + nn;
        int n = n0 + row;
        float sum = 0.f, cv = 0.f;
        if (n < NN) {
            int s = off[n], e = s + deg[n];
            float sum2 = 0.f;
            int k = s;
            for (; k + 1 < e; k += 2) {
                sum  += h2f(m_edge[(size_t)k * FH + lane]);
                sum2 += h2f(m_edge[(size_t)(k + 1) * FH + lane]);
                if (lane < 3)
                    cv += cwrel[(size_t)k * 3 + lane] + cwrel[(size_t)(k + 1) * 3 + lane];
            }
            if (k < e) {
                sum += h2f(m_edge[(size_t)k * FH + lane]);
                if (lane < 3) cv += cwrel[(size_t)k * 3 + lane];
            }
            sum += sum2;
            if (lane < 3) coors_out[n * 3 + lane] = coors_in[n * 3 + lane] + cv;
        }
        sh[row * HS + 64 + lane] = f2h(sum);
    }
    __syncthreads();

    half8 af[4][4];
    #pragma unroll
    for (int m = 0; m < 4; m++)
        #pragma unroll
        for (int kt = 0; kt < 4; kt++)
            af[m][kt] = *(const half8*)(sh + (m * 16 + lc) * HS + kt * 32 + quad * 8);
    #pragma unroll
    for (int i = 0; i < 2; i++) {
        int nt = wid + i * 4;
        float bias = b1[nt * 16 + lc];
        float4v acc[4];
        #pragma unroll
        for (int m = 0; m < 4; m++) acc[m] = (float4v){bias, bias, bias, bias};
        #pragma unroll
        for (int kt = 0; kt < 4; kt++) {
            half8 bh = ((const half8*)(W1f + (size_t)(nt * 4 + kt) * 512))[lane];
            #pragma unroll
            for (int m = 0; m < 4; m++)
                acc[m] = __builtin_amdgcn_mfma_f32_16x16x32_f16(af[m][kt], bh, acc[m], 0, 0, 0);
        }
        #pragma unroll
        for (int m = 0; m < 4; m++)
            #pragma unroll
            for (int r = 0; r < 4; r++)
                sg[(m * 16 + quad * 4 + r) * HS + nt * 16 + lc] = f2h(silu_f(acc[m][r]));
    }
    __syncthreads();

    {
        int nt = wid;
        float bias = b2[nt * 16 + lc];
        float4v acc[4];
        #pragma unroll
        for (int m = 0; m < 4; m++) acc[m] = (float4v){bias, bias, bias, bias};
        #pragma unroll
        for (int kt = 0; kt < 4; kt++) {
            half8 bh = ((const half8*)(W2f + (size_t)(nt * 4 + kt) * 512))[lane];
            #pragma unroll
            for (int m = 0; m < 4; m++) {
                half8 a = *(const half8*)(sg + (m * 16 + lc) * HS + kt * 32 + quad * 8);
                acc[m] = __builtin_amdgcn_mfma_f32_16x16x32_f16(a, bh, acc[m], 0, 0, 0);
            }
        }
        #pragma unroll
        for (int m = 0; m < 4; m++)
            #pragma unroll
            for (int r = 0; r < 4; r++) {
                int row = m * 16 + quad * 4 + r;
                size_t idx = (size_t)(n0 + row) * FH + nt * 16 + lc;
                float nv = feats[idx] + acc[m][r];   // residual in fp32
                feats[idx] = nv;
                featsh[idx] = f2h(nv);
            }
    }
}

__global__ void final_kernel(const float* __restrict__ feats, const float* __restrict__ linW,
                             const float* __restrict__ linb, float* __restrict__ out) {
    int t = blockIdx.x * 256 + threadIdx.x;
    int n = t >> 6;
    int lane = threadIdx.x & 63;
    if (n >= NN) return;
    float v = feats[(size_t)n * FH + lane] * linW[lane];
    #pragma unroll
    for (int off = 32; off > 0; off >>= 1) v += __shfl_down(v, off);
    if (lane == 0) out[n] = v + linb[0];
}

extern "C" void kernel_launch(void* const* d_in, const int* in_sizes, int n_in,
                              void* d_out, int out_size, void* d_ws, size_t ws_size,
                              hipStream_t stream) {
    const float* x      = (const float*)d_in[0];
    const float* pos    = (const float*)d_in[1];
    const int*   ei     = (const int*)d_in[2];
    const float* eattr  = (const float*)d_in[3];
    const float* embedW = (const float*)d_in[4];
    const float* embedb = (const float*)d_in[5];
    const float* eW1    = (const float*)d_in[6];
    const float* eb1    = (const float*)d_in[7];
    const float* eW2    = (const float*)d_in[8];
    const float* eb2    = (const float*)d_in[9];
    const float* cW1    = (const float*)d_in[10];
    const float* cb1    = (const float*)d_in[11];
    const float* cW2    = (const float*)d_in[12];
    const float* cb2    = (const float*)d_in[13];
    const float* nW1    = (const float*)d_in[14];
    const float* nb1    = (const float*)d_in[15];
    const float* nW2    = (const float*)d_in[16];
    const float* nb2    = (const float*)d_in[17];
    const float* linW   = (const float*)d_in[18];
    const float* linb   = (const float*)d_in[19];
    float* out = (float*)d_out;

    char* wp = (char*)d_ws;
    auto alloc = [&](size_t bytes) { void* p = wp; wp += (bytes + 255) & ~(size_t)255; return p; };

    const int W1F_L  = 17 * 5 * 512;
    const int W2F_L  = 4 * 9 * 512;
    const int CW1F_L = 16 * 2 * 512;
    const int NW1F_L = 8 * 4 * 512;
    const int NW2F_L = 4 * 4 * 512;

    float* feats  = (float*)alloc((size_t)NNP * FH * 4);
    short* featsh = (short*)alloc((size_t)NNP * FH * 2);
    float* cA     = (float*)alloc((size_t)NN * 3 * 4);
    float* cB     = (float*)alloc((size_t)NN * 3 * 4);
    short* W1f    = (short*)alloc((size_t)3 * W1F_L * 2);
    short* W2f    = (short*)alloc((size_t)3 * W2F_L * 2);
    short* cW1f   = (short*)alloc((size_t)3 * CW1F_L * 2);
    short* nW1f   = (short*)alloc((size_t)3 * NW1F_L * 2);
    short* nW2f   = (short*)alloc((size_t)3 * NW2F_L * 2);
    float* b1p    = (float*)alloc((size_t)3 * 272 * 4);
    int*   deg    = (int*)alloc((size_t)(NN + 1) * 4);   // deg[NN] = global cursor
    int*   off    = (int*)alloc((size_t)NN * 4);
    int*   cursor = (int*)alloc((size_t)NN * 4);
    int*   erow   = (int*)alloc((size_t)NE * 4);
    int*   ecol   = (int*)alloc((size_t)NE * 4);
    float* eattrp = (float*)alloc((size_t)NE * 4);
    short* m_edge = (short*)alloc((size_t)NE * FH * 2);
    float* cwrel  = (float*)alloc((size_t)NE * 3 * 4);
    int* gcount = deg + NN;

    prep_all<<<(309552 + 255) / 256, 256, 0, stream>>>(
        eW1, eW2, cW1, nW1, nW2, eb1,
        W1f, W2f, cW1f, nW1f, nW2f, b1p);

    hipMemsetAsync(deg, 0, (size_t)(NN + 1) * 4, stream);
    hist_kernel<<<(NE + 255) / 256, 256, 0, stream>>>(ei, deg);
    alloc_kernel<<<(NN + 255) / 256, 256, 0, stream>>>(deg, off, cursor, gcount);
    fill_kernel<<<(NE + 255) / 256, 256, 0, stream>>>(ei, eattr, cursor, erow, ecol, eattrp);

    embed_kernel<<<(NN * FH + 255) / 256, 256, 0, stream>>>(x, embedW, embedb, pos, feats, featsh, cA);

    float* ccur = cA;
    float* cnext = cB;
    for (int l = 0; l < 3; l++) {
        edge_fused<<<NE / 64, 256, 0, stream>>>(
            erow, ecol, eattrp, featsh, ccur,
            W1f + (size_t)l * W1F_L, b1p + l * 272,
            W2f + (size_t)l * W2F_L, eb2 + l * 64,
            cW1f + (size_t)l * CW1F_L, cb1 + l * 256,
            cW2 + l * 256, cb2 + l,
            m_edge, cwrel);
        agg_node<<<NNP / 64, 256, 0, stream>>>(
            off, deg, m_edge, cwrel, ccur, cnext, feats, featsh,
            nW1f + (size_t)l * NW1F_L, nb1 + l * 128,
            nW2f + (size_t)l * NW2F_L, nb2 + l * 64);
        float* tmp = ccur; ccur = cnext; cnext = tmp;
    }
    final_kernel<<<(NN * FH) / 256, 256, 0, stream>>>(feats, linW, linb, out);
}

// Round 14
// 639.279 us; speedup vs baseline: 1.3739x; 1.0318x over previous
//
#include <hip/hip_runtime.h>
#include <hip/hip_bf16.h>

#define NN 50000
#define NNP 50048   // padded to 64-node blocks
#define NE 400000
#define FH 64
#define NTILES (NE / 64)   // 6250
#define CHUNK 782          // ceil(6250/8) per XCD

typedef __attribute__((ext_vector_type(8))) short short8;
typedef __attribute__((ext_vector_type(8))) _Float16 half8;
typedef __attribute__((ext_vector_type(4))) float float4v;

__device__ __forceinline__ float silu_f(float x) {
    return x * __builtin_amdgcn_rcpf(1.0f + __expf(-x));
}
__device__ __forceinline__ short f2h(float f) {
    _Float16 h = (_Float16)f;
    return *(short*)&h;
}
__device__ __forceinline__ float h2f(short s) {
    _Float16 h = *(_Float16*)&s;
    return (float)h;
}

// ---------------- mega weight prep (single fp16 frags) + deg zeroing ----------------
__device__ __forceinline__ void frag_body(const float* __restrict__ src,
                                          short* __restrict__ dst,
                                          int t, int K, int N, int KT, int dup,
                                          int perL, int srcL) {
    int l = t / perL, tt = t - l * perL;
    int j = tt & 7, lane = (tt >> 3) & 63, frag = tt >> 9;
    int nt = frag / KT, kt = frag - nt * KT;
    int k = kt * 32 + ((lane >> 4) << 3) + j;
    int n = nt * 16 + (lane & 15);
    if (k == dup) k = dup - 1;
    float v = (k < K && n < N) ? src[(size_t)l * srcL + k * N + n] : 0.f;
    dst[t] = f2h(v);
}

__global__ void prep_all(const float* __restrict__ eW1, const float* __restrict__ eW2,
                         const float* __restrict__ cW1, const float* __restrict__ nW1,
                         const float* __restrict__ nW2, const float* __restrict__ eb1,
                         short* W1f, short* W2f, short* cW1f, short* nW1f,
                         short* nW2f, float* b1p, int* __restrict__ deg) {
    int t = blockIdx.x * 256 + threadIdx.x;
    if (t < 130560) { frag_body(eW1, W1f, t, 131, 260, 5, 130, 43520, 33800); return; }
    t -= 130560;
    if (t < 55296) { frag_body(eW2, W2f, t, 260, 64, 9, -1, 18432, 16640); return; }
    t -= 55296;
    if (t < 49152) { frag_body(cW1, cW1f, t, 64, 256, 2, -1, 16384, 16384); return; }
    t -= 49152;
    if (t < 49152) { frag_body(nW1, nW1f, t, 128, 128, 4, -1, 16384, 16384); return; }
    t -= 49152;
    if (t < 24576) { frag_body(nW2, nW2f, t, 128, 64, 4, -1, 8192, 8192); return; }
    t -= 24576;
    if (t < 816) { int l = t / 272, c = t - l * 272; b1p[t] = (c < 260) ? eb1[l * 260 + c] : 0.f; return; }
    t -= 816;
    if (t < NN + 1) deg[t] = 0;   // replaces hipMemsetAsync
}

__global__ void embed_kernel(const float* __restrict__ x, const float* __restrict__ W,
                             const float* __restrict__ b, const float* __restrict__ pos,
                             float* __restrict__ feats, short* __restrict__ featsh,
                             float* __restrict__ cA) {
    int t = blockIdx.x * 256 + threadIdx.x;
    if (t >= NN * FH) return;
    int n = t >> 6, hcol = t & 63;
    float acc = b[hcol];
    #pragma unroll
    for (int k = 0; k < 8; k++) acc += x[n * 8 + k] * W[k * FH + hcol];
    feats[t] = acc;
    featsh[t] = f2h(acc);
    if (hcol < 3) cA[n * 3 + hcol] = pos[n * 3 + hcol];
}

// ---------------- CSR build (block scan + global cursor) ----------------
__global__ void hist_kernel(const int* __restrict__ ei, int* __restrict__ deg) {
    int e = blockIdx.x * 256 + threadIdx.x;
    if (e >= NE) return;
    atomicAdd(&deg[ei[e]], 1);
}

__global__ void alloc_kernel(const int* __restrict__ deg, int* __restrict__ off,
                             int* __restrict__ cursor, int* __restrict__ gcount) {
    __shared__ int s[256];
    __shared__ int base;
    int t = threadIdx.x, n = blockIdx.x * 256 + t;
    int d = (n < NN) ? deg[n] : 0;
    s[t] = d;
    __syncthreads();
    for (int st = 1; st < 256; st <<= 1) {
        int v = (t >= st) ? s[t - st] : 0;
        __syncthreads();
        s[t] += v;
        __syncthreads();
    }
    if (t == 255) base = atomicAdd(gcount, s[255]);
    __syncthreads();
    if (n < NN) { int o = base + s[t] - d; off[n] = o; cursor[n] = o; }
}

__global__ void fill_kernel(const int* __restrict__ ei, const float* __restrict__ eattr,
                            int* __restrict__ cursor, int* __restrict__ erow,
                            int* __restrict__ ecol, float* __restrict__ eattrp) {
    int e = blockIdx.x * 256 + threadIdx.x;
    if (e >= NE) return;
    int r = ei[e];
    int p = atomicAdd(&cursor[r], 1);
    erow[p] = r;
    ecol[p] = ei[NE + e];
    eattrp[p] = eattr[e];
}

// ---------------- fused MFMA edge pipeline (fp16, r10-proven structure) ----------------
// NOTE: 3 blocks/CU measured sweet spot (4/CU thrashed L2: r11). No non-temporal
// hints (r12 regression). XCD-aware swizzle: block b runs on XCD b%8 (round-robin
// dispatch heuristic); give XCD x the contiguous CSR range [x*782, (x+1)*782) so
// each XCD's 4MB L2 sees ~1/8 of the featsh row-gather working set.
#define SE_STRIDE 168   // shorts
#define H1_STRIDE 296
#define M_STRIDE  72

__global__ __launch_bounds__(256, 3) void edge_fused(
    const int* __restrict__ erow, const int* __restrict__ ecol,
    const float* __restrict__ eattrp,
    const short* __restrict__ featsh, const float* __restrict__ coors,
    const short* __restrict__ W1f, const float* __restrict__ b1p,
    const short* __restrict__ W2f, const float* __restrict__ b2,
    const short* __restrict__ cW1f, const float* __restrict__ cb1,
    const float* __restrict__ cW2, const float* __restrict__ cb2,
    short* __restrict__ m_edge, float* __restrict__ cwrel)
{
    __shared__ char smem[48896];
    short* sE   = (short*)smem;               // [0,21504)
    short* sH1  = (short*)smem;               // [0,37888) overlays sE
    short* sM   = (short*)(smem + 37888);     // [37888,47104)
    float* sRel = (float*)(smem + 47104);
    float* cwbuf = (float*)(smem + 47872);

    int b = blockIdx.x;
    int kb = (b & 7) * CHUNK + (b >> 3);
    if (kb >= NTILES) return;
    int k0 = kb * 64;

    int t = threadIdx.x;
    int lane = t & 63, wid = t >> 6, quad = lane >> 4, lc = lane & 15;

    // ---- phase 1: gather e_in ----
    {
        int el = t >> 2, sub = t & 3, k = k0 + el;
        int rI = erow[k], cI = ecol[k];
        const short8* fr = (const short8*)(featsh + (size_t)rI * FH);
        const short8* fc = (const short8*)(featsh + (size_t)cI * FH);
        short* er = sE + el * SE_STRIDE;
        *(short8*)(er + sub * 16) = fr[sub * 2];
        *(short8*)(er + sub * 16 + 8) = fr[sub * 2 + 1];
        *(short8*)(er + 64 + sub * 16) = fc[sub * 2];
        *(short8*)(er + 64 + sub * 16 + 8) = fc[sub * 2 + 1];
        #pragma unroll
        for (int i = 0; i < 10; i++) er[128 + sub * 10 + i] = 0;
        if (sub == 0) {
            float rx = coors[rI * 3 + 0] - coors[cI * 3 + 0];
            float ry = coors[rI * 3 + 1] - coors[cI * 3 + 1];
            float rz = coors[rI * 3 + 2] - coors[cI * 3 + 2];
            float dist = rx * rx + ry * ry + rz * rz;
            short dh = f2h(dist);
            er[128] = f2h(eattrp[k]);
            er[129] = dh;
            er[130] = f2h(dist - h2f(dh));   // dist hi/lo columns (W1 row 130 = dup of 129)
            sRel[el * 3 + 0] = rx; sRel[el * 3 + 1] = ry; sRel[el * 3 + 2] = rz;
        }
    }
    __syncthreads();

    // ---- phase 2: A fragments to registers, fence before overlay ----
    half8 af[4][5];
    #pragma unroll
    for (int m = 0; m < 4; m++)
        #pragma unroll
        for (int kt = 0; kt < 5; kt++)
            af[m][kt] = *(const half8*)(sE + (m * 16 + lc) * SE_STRIDE + kt * 32 + quad * 8);
    __syncthreads();

    // ---- phase 3: GEMM1 e_in[64x160] @ W1[160x272] -> silu -> sH1 ----
    {
        *(long long*)(sH1 + (t >> 2) * H1_STRIDE + 272 + (t & 3) * 4) = 0LL;
        #pragma unroll
        for (int i = 0; i < 4; i++) {
            int nt = wid + i * 4;
            float bias = b1p[nt * 16 + lc];
            float4v acc[4];
            #pragma unroll
            for (int m = 0; m < 4; m++) acc[m] = (float4v){bias, bias, bias, bias};
            #pragma unroll
            for (int kt = 0; kt < 5; kt++) {
                half8 bh = ((const half8*)(W1f + (size_t)(nt * 5 + kt) * 512))[lane];
                #pragma unroll
                for (int m = 0; m < 4; m++)
                    acc[m] = __builtin_amdgcn_mfma_f32_16x16x32_f16(af[m][kt], bh, acc[m], 0, 0, 0);
            }
            #pragma unroll
            for (int m = 0; m < 4; m++)
                #pragma unroll
                for (int r = 0; r < 4; r++)
                    sH1[(m * 16 + quad * 4 + r) * H1_STRIDE + nt * 16 + lc] = f2h(silu_f(acc[m][r]));
        }
        if (wid == 0) {
            const int nt = 16;
            float bias = b1p[nt * 16 + lc];
            float4v acc[4];
            #pragma unroll
            for (int m = 0; m < 4; m++) acc[m] = (float4v){bias, bias, bias, bias};
            #pragma unroll
            for (int kt = 0; kt < 5; kt++) {
                half8 bh = ((const half8*)(W1f + (size_t)(nt * 5 + kt) * 512))[lane];
                #pragma unroll
                for (int m = 0; m < 4; m++)
                    acc[m] = __builtin_amdgcn_mfma_f32_16x16x32_f16(af[m][kt], bh, acc[m], 0, 0, 0);
            }
            #pragma unroll
            for (int m = 0; m < 4; m++)
                #pragma unroll
                for (int r = 0; r < 4; r++)
                    sH1[(m * 16 + quad * 4 + r) * H1_STRIDE + nt * 16 + lc] = f2h(silu_f(acc[m][r]));
        }
    }
    __syncthreads();

    // ---- phase 4: GEMM2 H1[64x288] @ W2[288x64] -> silu -> sM ----
    {
        int nt = wid;
        float bias = b2[nt * 16 + lc];
        float4v acc[4];
        #pragma unroll
        for (int m = 0; m < 4; m++) acc[m] = (float4v){bias, bias, bias, bias};
        #pragma unroll
        for (int kt = 0; kt < 9; kt++) {
            half8 bh = ((const half8*)(W2f + (size_t)(nt * 9 + kt) * 512))[lane];
            #pragma unroll
            for (int m = 0; m < 4; m++) {
                half8 a = *(const half8*)(sH1 + (m * 16 + lc) * H1_STRIDE + kt * 32 + quad * 8);
                acc[m] = __builtin_amdgcn_mfma_f32_16x16x32_f16(a, bh, acc[m], 0, 0, 0);
            }
        }
        #pragma unroll
        for (int m = 0; m < 4; m++)
            #pragma unroll
            for (int r = 0; r < 4; r++)
                sM[(m * 16 + quad * 4 + r) * M_STRIDE + nt * 16 + lc] = f2h(silu_f(acc[m][r]));
    }
    __syncthreads();

    // ---- phase 5: m -> global + GEMM3 ----
    {
        int row = t >> 2, c0 = (t & 3) * 16;
        short8 v0 = *(const short8*)(sM + row * M_STRIDE + c0);
        short8 v1 = *(const short8*)(sM + row * M_STRIDE + c0 + 8);
        short* mg = m_edge + (size_t)(k0 + row) * FH + c0;
        *(short8*)(mg) = v0;
        *(short8*)(mg + 8) = v1;
    }
    {
        half8 ag[4][2];
        #pragma unroll
        for (int m = 0; m < 4; m++)
            #pragma unroll
            for (int kt = 0; kt < 2; kt++)
                ag[m][kt] = *(const half8*)(sM + (m * 16 + lc) * M_STRIDE + kt * 32 + quad * 8);
        float cwpart[4][4];
        #pragma unroll
        for (int m = 0; m < 4; m++)
            #pragma unroll
            for (int r = 0; r < 4; r++) cwpart[m][r] = 0.f;
        #pragma unroll
        for (int i = 0; i < 4; i++) {
            int nt = wid + i * 4;
            float bias = cb1[nt * 16 + lc];
            float4v acc[4];
            #pragma unroll
            for (int m = 0; m < 4; m++) acc[m] = (float4v){bias, bias, bias, bias};
            #pragma unroll
            for (int kt = 0; kt < 2; kt++) {
                half8 bh = ((const half8*)(cW1f + (size_t)(nt * 2 + kt) * 512))[lane];
                #pragma unroll
                for (int m = 0; m < 4; m++)
                    acc[m] = __builtin_amdgcn_mfma_f32_16x16x32_f16(ag[m][kt], bh, acc[m], 0, 0, 0);
            }
            float wv = cW2[nt * 16 + lc];
            #pragma unroll
            for (int m = 0; m < 4; m++)
                #pragma unroll
                for (int r = 0; r < 4; r++)
                    cwpart[m][r] += silu_f(acc[m][r]) * wv;
        }
        #pragma unroll
        for (int m = 0; m < 4; m++)
            #pragma unroll
            for (int r = 0; r < 4; r++) {
                float p = cwpart[m][r];
                p += __shfl_xor(p, 1);
                p += __shfl_xor(p, 2);
                p += __shfl_xor(p, 4);
                p += __shfl_xor(p, 8);
                if (lc == 0) cwbuf[wid * 64 + m * 16 + quad * 4 + r] = p;
            }
    }
    __syncthreads();

    if (t < 64) {
        float cw = cb2[0] + cwbuf[t] + cwbuf[64 + t] + cwbuf[128 + t] + cwbuf[192 + t];
        float* o = cwrel + (size_t)(k0 + t) * 3;
        o[0] = cw * sRel[t * 3 + 0];
        o[1] = cw * sRel[t * 3 + 1];
        o[2] = cw * sRel[t * 3 + 2];
    }
}

// ---------------- fused aggregation + node MLP (fp16) ----------------
#define HS 136
__global__ __launch_bounds__(256, 4) void agg_node(
    const int* __restrict__ off, const int* __restrict__ deg,
    const short* __restrict__ m_edge, const float* __restrict__ cwrel,
    const float* __restrict__ coors_in, float* __restrict__ coors_out,
    float* __restrict__ feats, short* __restrict__ featsh,
    const short* __restrict__ W1f, const float* __restrict__ b1,
    const short* __restrict__ W2f, const float* __restrict__ b2)
{
    __shared__ short sh[64 * HS];   // h = [featsh | agg(m)]
    __shared__ short sg[64 * HS];   // silu(h@W1+b1)
    int t = threadIdx.x, lane = t & 63, wid = t >> 6, quad = lane >> 4, lc = lane & 15;
    int n0 = blockIdx.x * 64;

    {
        int row = t >> 2, sub = t & 3;
        const short8* fp = (const short8*)(featsh + (size_t)(n0 + row) * FH);
        *(short8*)(sh + row * HS + sub * 16) = fp[sub * 2];
        *(short8*)(sh + row * HS + sub * 16 + 8) = fp[sub * 2 + 1];
    }
    // k-loop unrolled x4 with split accumulators to overlap L2 load latency
    for (int nn = 0; nn < 16; nn++) {
        int row = wid * 16 + nn;
        int n = n0 + row;
        float sum = 0.f, cv = 0.f;
        if (n < NN) {
            int s = off[n], e = s + deg[n];
            float s0 = 0.f, s1 = 0.f, s2 = 0.f, s3 = 0.f;
            int k = s;
            for (; k + 3 < e; k += 4) {
                s0 += h2f(m_edge[(size_t)k * FH + lane]);
                s1 += h2f(m_edge[(size_t)(k + 1) * FH + lane]);
                s2 += h2f(m_edge[(size_t)(k + 2) * FH + lane]);
                s3 += h2f(m_edge[(size_t)(k + 3) * FH + lane]);
                if (lane < 3)
                    cv += (cwrel[(size_t)k * 3 + lane] + cwrel[(size_t)(k + 1) * 3 + lane])
                        + (cwrel[(size_t)(k + 2) * 3 + lane] + cwrel[(size_t)(k + 3) * 3 + lane]);
            }
            for (; k < e; k++) {
                s0 += h2f(m_edge[(size_t)k * FH + lane]);
                if (lane < 3) cv += cwrel[(size_t)k * 3 + lane];
            }
            sum = (s0 + s1) + (s2 + s3);
            if (lane < 3) coors_out[n * 3 + lane] = coors_in[n * 3 + lane] + cv;
        }
        sh[row * HS + 64 + lane] = f2h(sum);
    }
    __syncthreads();

    half8 af[4][4];
    #pragma unroll
    for (int m = 0; m < 4; m++)
        #pragma unroll
        for (int kt = 0; kt < 4; kt++)
            af[m][kt] = *(const half8*)(sh + (m * 16 + lc) * HS + kt * 32 + quad * 8);
    #pragma unroll
    for (int i = 0; i < 2; i++) {
        int nt = wid + i * 4;
        float bias = b1[nt * 16 + lc];
        float4v acc[4];
        #pragma unroll
        for (int m = 0; m < 4; m++) acc[m] = (float4v){bias, bias, bias, bias};
        #pragma unroll
        for (int kt = 0; kt < 4; kt++) {
            half8 bh = ((const half8*)(W1f + (size_t)(nt * 4 + kt) * 512))[lane];
            #pragma unroll
            for (int m = 0; m < 4; m++)
                acc[m] = __builtin_amdgcn_mfma_f32_16x16x32_f16(af[m][kt], bh, acc[m], 0, 0, 0);
        }
        #pragma unroll
        for (int m = 0; m < 4; m++)
            #pragma unroll
            for (int r = 0; r < 4; r++)
                sg[(m * 16 + quad * 4 + r) * HS + nt * 16 + lc] = f2h(silu_f(acc[m][r]));
    }
    __syncthreads();

    {
        int nt = wid;
        float bias = b2[nt * 16 + lc];
        float4v acc[4];
        #pragma unroll
        for (int m = 0; m < 4; m++) acc[m] = (float4v){bias, bias, bias, bias};
        #pragma unroll
        for (int kt = 0; kt < 4; kt++) {
            half8 bh = ((const half8*)(W2f + (size_t)(nt * 4 + kt) * 512))[lane];
            #pragma unroll
            for (int m = 0; m < 4; m++) {
                half8 a = *(const half8*)(sg + (m * 16 + lc) * HS + kt * 32 + quad * 8);
                acc[m] = __builtin_amdgcn_mfma_f32_16x16x32_f16(a, bh, acc[m], 0, 0, 0);
            }
        }
        #pragma unroll
        for (int m = 0; m < 4; m++)
            #pragma unroll
            for (int r = 0; r < 4; r++) {
                int row = m * 16 + quad * 4 + r;
                size_t idx = (size_t)(n0 + row) * FH + nt * 16 + lc;
                float nv = feats[idx] + acc[m][r];   // residual in fp32
                feats[idx] = nv;
                featsh[idx] = f2h(nv);
            }
    }
}

__global__ void final_kernel(const float* __restrict__ feats, const float* __restrict__ linW,
                             const float* __restrict__ linb, float* __restrict__ out) {
    int t = blockIdx.x * 256 + threadIdx.x;
    int n = t >> 6;
    int lane = threadIdx.x & 63;
    if (n >= NN) return;
    float v = feats[(size_t)n * FH + lane] * linW[lane];
    #pragma unroll
    for (int off = 32; off > 0; off >>= 1) v += __shfl_down(v, off);
    if (lane == 0) out[n] = v + linb[0];
}

extern "C" void kernel_launch(void* const* d_in, const int* in_sizes, int n_in,
                              void* d_out, int out_size, void* d_ws, size_t ws_size,
                              hipStream_t stream) {
    const float* x      = (const float*)d_in[0];
    const float* pos    = (const float*)d_in[1];
    const int*   ei     = (const int*)d_in[2];
    const float* eattr  = (const float*)d_in[3];
    const float* embedW = (const float*)d_in[4];
    const float* embedb = (const float*)d_in[5];
    const float* eW1    = (const float*)d_in[6];
    const float* eb1    = (const float*)d_in[7];
    const float* eW2    = (const float*)d_in[8];
    const float* eb2    = (const float*)d_in[9];
    const float* cW1    = (const float*)d_in[10];
    const float* cb1    = (const float*)d_in[11];
    const float* cW2    = (const float*)d_in[12];
    const float* cb2    = (const float*)d_in[13];
    const float* nW1    = (const float*)d_in[14];
    const float* nb1    = (const float*)d_in[15];
    const float* nW2    = (const float*)d_in[16];
    const float* nb2    = (const float*)d_in[17];
    const float* linW   = (const float*)d_in[18];
    const float* linb   = (const float*)d_in[19];
    float* out = (float*)d_out;

    char* wp = (char*)d_ws;
    auto alloc = [&](size_t bytes) { void* p = wp; wp += (bytes + 255) & ~(size_t)255; return p; };

    const int W1F_L  = 17 * 5 * 512;
    const int W2F_L  = 4 * 9 * 512;
    const int CW1F_L = 16 * 2 * 512;
    const int NW1F_L = 8 * 4 * 512;
    const int NW2F_L = 4 * 4 * 512;

    float* feats  = (float*)alloc((size_t)NNP * FH * 4);
    short* featsh = (short*)alloc((size_t)NNP * FH * 2);
    float* cA     = (float*)alloc((size_t)NN * 3 * 4);
    float* cB     = (float*)alloc((size_t)NN * 3 * 4);
    short* W1f    = (short*)alloc((size_t)3 * W1F_L * 2);
    short* W2f    = (short*)alloc((size_t)3 * W2F_L * 2);
    short* cW1f   = (short*)alloc((size_t)3 * CW1F_L * 2);
    short* nW1f   = (short*)alloc((size_t)3 * NW1F_L * 2);
    short* nW2f   = (short*)alloc((size_t)3 * NW2F_L * 2);
    float* b1p    = (float*)alloc((size_t)3 * 272 * 4);
    int*   deg    = (int*)alloc((size_t)(NN + 1) * 4);   // deg[NN] = global cursor
    int*   off    = (int*)alloc((size_t)NN * 4);
    int*   cursor = (int*)alloc((size_t)NN * 4);
    int*   erow   = (int*)alloc((size_t)NE * 4);
    int*   ecol   = (int*)alloc((size_t)NE * 4);
    float* eattrp = (float*)alloc((size_t)NE * 4);
    short* m_edge = (short*)alloc((size_t)NE * FH * 2);
    float* cwrel  = (float*)alloc((size_t)NE * 3 * 4);
    int* gcount = deg + NN;

    // prep: weight frags + b1 pad + deg zeroing (359553 work items)
    prep_all<<<(359553 + 255) / 256, 256, 0, stream>>>(
        eW1, eW2, cW1, nW1, nW2, eb1,
        W1f, W2f, cW1f, nW1f, nW2f, b1p, deg);

    hist_kernel<<<(NE + 255) / 256, 256, 0, stream>>>(ei, deg);
    alloc_kernel<<<(NN + 255) / 256, 256, 0, stream>>>(deg, off, cursor, gcount);
    fill_kernel<<<(NE + 255) / 256, 256, 0, stream>>>(ei, eattr, cursor, erow, ecol, eattrp);

    embed_kernel<<<(NN * FH + 255) / 256, 256, 0, stream>>>(x, embedW, embedb, pos, feats, featsh, cA);

    float* ccur = cA;
    float* cnext = cB;
    for (int l = 0; l < 3; l++) {
        edge_fused<<<8 * CHUNK, 256, 0, stream>>>(
            erow, ecol, eattrp, featsh, ccur,
            W1f + (size_t)l * W1F_L, b1p + l * 272,
            W2f + (size_t)l * W2F_L, eb2 + l * 64,
            cW1f + (size_t)l * CW1F_L, cb1 + l * 256,
            cW2 + l * 256, cb2 + l,
            m_edge, cwrel);
        agg_node<<<NNP / 64, 256, 0, stream>>>(
            off, deg, m_edge, cwrel, ccur, cnext, feats, featsh,
            nW1f + (size_t)l * NW1F_L, nb1 + l * 128,
            nW2f + (size_t)l * NW2F_L, nb2 + l * 64);
        float* tmp = ccur; ccur = cnext; cnext = tmp;
    }
    final_kernel<<<(NN * FH) / 256, 256, 0, stream>>>(feats, linW, linb, out);
}

// Round 15
// 582.242 us; speedup vs baseline: 1.5085x; 1.0980x over previous
//
#include <hip/hip_runtime.h>
#include <hip/hip_bf16.h>

#define NN 50000
#define NNP 50048   // padded to 64-node blocks
#define NE 400000
#define FH 64
#define NTILES (NE / 64)   // 6250
#define CHUNK 782          // ceil(6250/8) per XCD

typedef __attribute__((ext_vector_type(8))) short short8;
typedef __attribute__((ext_vector_type(8))) _Float16 half8;
typedef __attribute__((ext_vector_type(4))) float float4v;

__device__ __forceinline__ float silu_f(float x) {
    return x * __builtin_amdgcn_rcpf(1.0f + __expf(-x));
}
__device__ __forceinline__ short f2h(float f) {
    _Float16 h = (_Float16)f;
    return *(short*)&h;
}
__device__ __forceinline__ float h2f(short s) {
    _Float16 h = *(_Float16*)&s;
    return (float)h;
}

// ---------------- mega weight prep (single fp16 frags) + deg zeroing ----------------
__device__ __forceinline__ void frag_body(const float* __restrict__ src,
                                          short* __restrict__ dst,
                                          int t, int K, int N, int KT, int dup,
                                          int perL, int srcL) {
    int l = t / perL, tt = t - l * perL;
    int j = tt & 7, lane = (tt >> 3) & 63, frag = tt >> 9;
    int nt = frag / KT, kt = frag - nt * KT;
    int k = kt * 32 + ((lane >> 4) << 3) + j;
    int n = nt * 16 + (lane & 15);
    if (k == dup) k = dup - 1;
    float v = (k < K && n < N) ? src[(size_t)l * srcL + k * N + n] : 0.f;
    dst[t] = f2h(v);
}

__global__ void prep_all(const float* __restrict__ eW1, const float* __restrict__ eW2,
                         const float* __restrict__ cW1, const float* __restrict__ nW1,
                         const float* __restrict__ nW2, const float* __restrict__ eb1,
                         short* W1f, short* W2f, short* cW1f, short* nW1f,
                         short* nW2f, float* b1p, int* __restrict__ deg) {
    int t = blockIdx.x * 256 + threadIdx.x;
    if (t < 130560) { frag_body(eW1, W1f, t, 131, 260, 5, 130, 43520, 33800); return; }
    t -= 130560;
    if (t < 55296) { frag_body(eW2, W2f, t, 260, 64, 9, -1, 18432, 16640); return; }
    t -= 55296;
    if (t < 49152) { frag_body(cW1, cW1f, t, 64, 256, 2, -1, 16384, 16384); return; }
    t -= 49152;
    if (t < 49152) { frag_body(nW1, nW1f, t, 128, 128, 4, -1, 16384, 16384); return; }
    t -= 49152;
    if (t < 24576) { frag_body(nW2, nW2f, t, 128, 64, 4, -1, 8192, 8192); return; }
    t -= 24576;
    if (t < 816) { int l = t / 272, c = t - l * 272; b1p[t] = (c < 260) ? eb1[l * 260 + c] : 0.f; return; }
    t -= 816;
    if (t < NN + 1) deg[t] = 0;   // replaces hipMemsetAsync
}

__global__ void embed_kernel(const float* __restrict__ x, const float* __restrict__ W,
                             const float* __restrict__ b, const float* __restrict__ pos,
                             float* __restrict__ feats, short* __restrict__ featsh,
                             float* __restrict__ cA) {
    int t = blockIdx.x * 256 + threadIdx.x;
    if (t >= NN * FH) return;
    int n = t >> 6, hcol = t & 63;
    float acc = b[hcol];
    #pragma unroll
    for (int k = 0; k < 8; k++) acc += x[n * 8 + k] * W[k * FH + hcol];
    feats[t] = acc;
    featsh[t] = f2h(acc);
    if (hcol < 3) cA[n * 3 + hcol] = pos[n * 3 + hcol];
}

// ---------------- CSR build (block scan + global cursor) ----------------
__global__ void hist_kernel(const int* __restrict__ ei, int* __restrict__ deg) {
    int e = blockIdx.x * 256 + threadIdx.x;
    if (e >= NE) return;
    atomicAdd(&deg[ei[e]], 1);
}

__global__ void alloc_kernel(const int* __restrict__ deg, int* __restrict__ off,
                             int* __restrict__ cursor, int* __restrict__ gcount) {
    __shared__ int s[256];
    __shared__ int base;
    int t = threadIdx.x, n = blockIdx.x * 256 + t;
    int d = (n < NN) ? deg[n] : 0;
    s[t] = d;
    __syncthreads();
    for (int st = 1; st < 256; st <<= 1) {
        int v = (t >= st) ? s[t - st] : 0;
        __syncthreads();
        s[t] += v;
        __syncthreads();
    }
    if (t == 255) base = atomicAdd(gcount, s[255]);
    __syncthreads();
    if (n < NN) { int o = base + s[t] - d; off[n] = o; cursor[n] = o; }
}

__global__ void fill_kernel(const int* __restrict__ ei, const float* __restrict__ eattr,
                            int* __restrict__ cursor, int* __restrict__ erow,
                            int* __restrict__ ecol, float* __restrict__ eattrp) {
    int e = blockIdx.x * 256 + threadIdx.x;
    if (e >= NE) return;
    int r = ei[e];
    int p = atomicAdd(&cursor[r], 1);
    erow[p] = r;
    ecol[p] = ei[NE + e];
    eattrp[p] = eattr[e];
}

// ---------------- fused MFMA edge pipeline (fp16, r10-proven structure) ----------------
// NOTE: 3 blocks/CU measured sweet spot (4/CU thrashed L2: r11). No non-temporal
// hints (r12 regression). do_cw=0 on the last layer: the coors path is dead there
// (reference discards final coors), skipping GEMM3 + cwrel entirely.
#define SE_STRIDE 168   // shorts
#define H1_STRIDE 296
#define M_STRIDE  72

__global__ __launch_bounds__(256, 3) void edge_fused(
    const int* __restrict__ erow, const int* __restrict__ ecol,
    const float* __restrict__ eattrp,
    const short* __restrict__ featsh, const float* __restrict__ coors,
    const short* __restrict__ W1f, const float* __restrict__ b1p,
    const short* __restrict__ W2f, const float* __restrict__ b2,
    const short* __restrict__ cW1f, const float* __restrict__ cb1,
    const float* __restrict__ cW2, const float* __restrict__ cb2,
    short* __restrict__ m_edge, float* __restrict__ cwrel, int do_cw)
{
    __shared__ char smem[48896];
    short* sE   = (short*)smem;               // [0,21504)
    short* sH1  = (short*)smem;               // [0,37888) overlays sE
    short* sM   = (short*)(smem + 37888);     // [37888,47104)
    float* sRel = (float*)(smem + 47104);
    float* cwbuf = (float*)(smem + 47872);

    int b = blockIdx.x;
    int kb = (b & 7) * CHUNK + (b >> 3);
    if (kb >= NTILES) return;
    int k0 = kb * 64;

    int t = threadIdx.x;
    int lane = t & 63, wid = t >> 6, quad = lane >> 4, lc = lane & 15;

    // ---- phase 1: gather e_in ----
    {
        int el = t >> 2, sub = t & 3, k = k0 + el;
        int rI = erow[k], cI = ecol[k];
        const short8* fr = (const short8*)(featsh + (size_t)rI * FH);
        const short8* fc = (const short8*)(featsh + (size_t)cI * FH);
        short* er = sE + el * SE_STRIDE;
        *(short8*)(er + sub * 16) = fr[sub * 2];
        *(short8*)(er + sub * 16 + 8) = fr[sub * 2 + 1];
        *(short8*)(er + 64 + sub * 16) = fc[sub * 2];
        *(short8*)(er + 64 + sub * 16 + 8) = fc[sub * 2 + 1];
        #pragma unroll
        for (int i = 0; i < 10; i++) er[128 + sub * 10 + i] = 0;
        if (sub == 0) {
            float rx = coors[rI * 3 + 0] - coors[cI * 3 + 0];
            float ry = coors[rI * 3 + 1] - coors[cI * 3 + 1];
            float rz = coors[rI * 3 + 2] - coors[cI * 3 + 2];
            float dist = rx * rx + ry * ry + rz * rz;
            short dh = f2h(dist);
            er[128] = f2h(eattrp[k]);
            er[129] = dh;
            er[130] = f2h(dist - h2f(dh));   // dist hi/lo columns (W1 row 130 = dup of 129)
            sRel[el * 3 + 0] = rx; sRel[el * 3 + 1] = ry; sRel[el * 3 + 2] = rz;
        }
    }
    __syncthreads();

    // ---- phase 2: A fragments to registers, fence before overlay ----
    half8 af[4][5];
    #pragma unroll
    for (int m = 0; m < 4; m++)
        #pragma unroll
        for (int kt = 0; kt < 5; kt++)
            af[m][kt] = *(const half8*)(sE + (m * 16 + lc) * SE_STRIDE + kt * 32 + quad * 8);
    __syncthreads();

    // ---- phase 3: GEMM1 e_in[64x160] @ W1[160x272] -> silu -> sH1 ----
    {
        *(long long*)(sH1 + (t >> 2) * H1_STRIDE + 272 + (t & 3) * 4) = 0LL;
        #pragma unroll
        for (int i = 0; i < 4; i++) {
            int nt = wid + i * 4;
            float bias = b1p[nt * 16 + lc];
            float4v acc[4];
            #pragma unroll
            for (int m = 0; m < 4; m++) acc[m] = (float4v){bias, bias, bias, bias};
            #pragma unroll
            for (int kt = 0; kt < 5; kt++) {
                half8 bh = ((const half8*)(W1f + (size_t)(nt * 5 + kt) * 512))[lane];
                #pragma unroll
                for (int m = 0; m < 4; m++)
                    acc[m] = __builtin_amdgcn_mfma_f32_16x16x32_f16(af[m][kt], bh, acc[m], 0, 0, 0);
            }
            #pragma unroll
            for (int m = 0; m < 4; m++)
                #pragma unroll
                for (int r = 0; r < 4; r++)
                    sH1[(m * 16 + quad * 4 + r) * H1_STRIDE + nt * 16 + lc] = f2h(silu_f(acc[m][r]));
        }
        if (wid == 0) {
            const int nt = 16;
            float bias = b1p[nt * 16 + lc];
            float4v acc[4];
            #pragma unroll
            for (int m = 0; m < 4; m++) acc[m] = (float4v){bias, bias, bias, bias};
            #pragma unroll
            for (int kt = 0; kt < 5; kt++) {
                half8 bh = ((const half8*)(W1f + (size_t)(nt * 5 + kt) * 512))[lane];
                #pragma unroll
                for (int m = 0; m < 4; m++)
                    acc[m] = __builtin_amdgcn_mfma_f32_16x16x32_f16(af[m][kt], bh, acc[m], 0, 0, 0);
            }
            #pragma unroll
            for (int m = 0; m < 4; m++)
                #pragma unroll
                for (int r = 0; r < 4; r++)
                    sH1[(m * 16 + quad * 4 + r) * H1_STRIDE + nt * 16 + lc] = f2h(silu_f(acc[m][r]));
        }
    }
    __syncthreads();

    // ---- phase 4: GEMM2 H1[64x288] @ W2[288x64] -> silu -> sM ----
    {
        int nt = wid;
        float bias = b2[nt * 16 + lc];
        float4v acc[4];
        #pragma unroll
        for (int m = 0; m < 4; m++) acc[m] = (float4v){bias, bias, bias, bias};
        #pragma unroll
        for (int kt = 0; kt < 9; kt++) {
            half8 bh = ((const half8*)(W2f + (size_t)(nt * 9 + kt) * 512))[lane];
            #pragma unroll
            for (int m = 0; m < 4; m++) {
                half8 a = *(const half8*)(sH1 + (m * 16 + lc) * H1_STRIDE + kt * 32 + quad * 8);
                acc[m] = __builtin_amdgcn_mfma_f32_16x16x32_f16(a, bh, acc[m], 0, 0, 0);
            }
        }
        #pragma unroll
        for (int m = 0; m < 4; m++)
            #pragma unroll
            for (int r = 0; r < 4; r++)
                sM[(m * 16 + quad * 4 + r) * M_STRIDE + nt * 16 + lc] = f2h(silu_f(acc[m][r]));
    }
    __syncthreads();

    // ---- phase 5: m -> global (+ GEMM3 only when coors output is live) ----
    {
        int row = t >> 2, c0 = (t & 3) * 16;
        short8 v0 = *(const short8*)(sM + row * M_STRIDE + c0);
        short8 v1 = *(const short8*)(sM + row * M_STRIDE + c0 + 8);
        short* mg = m_edge + (size_t)(k0 + row) * FH + c0;
        *(short8*)(mg) = v0;
        *(short8*)(mg + 8) = v1;
    }
    if (do_cw) {
        half8 ag[4][2];
        #pragma unroll
        for (int m = 0; m < 4; m++)
            #pragma unroll
            for (int kt = 0; kt < 2; kt++)
                ag[m][kt] = *(const half8*)(sM + (m * 16 + lc) * M_STRIDE + kt * 32 + quad * 8);
        float cwpart[4][4];
        #pragma unroll
        for (int m = 0; m < 4; m++)
            #pragma unroll
            for (int r = 0; r < 4; r++) cwpart[m][r] = 0.f;
        #pragma unroll
        for (int i = 0; i < 4; i++) {
            int nt = wid + i * 4;
            float bias = cb1[nt * 16 + lc];
            float4v acc[4];
            #pragma unroll
            for (int m = 0; m < 4; m++) acc[m] = (float4v){bias, bias, bias, bias};
            #pragma unroll
            for (int kt = 0; kt < 2; kt++) {
                half8 bh = ((const half8*)(cW1f + (size_t)(nt * 2 + kt) * 512))[lane];
                #pragma unroll
                for (int m = 0; m < 4; m++)
                    acc[m] = __builtin_amdgcn_mfma_f32_16x16x32_f16(ag[m][kt], bh, acc[m], 0, 0, 0);
            }
            float wv = cW2[nt * 16 + lc];
            #pragma unroll
            for (int m = 0; m < 4; m++)
                #pragma unroll
                for (int r = 0; r < 4; r++)
                    cwpart[m][r] += silu_f(acc[m][r]) * wv;
        }
        #pragma unroll
        for (int m = 0; m < 4; m++)
            #pragma unroll
            for (int r = 0; r < 4; r++) {
                float p = cwpart[m][r];
                p += __shfl_xor(p, 1);
                p += __shfl_xor(p, 2);
                p += __shfl_xor(p, 4);
                p += __shfl_xor(p, 8);
                if (lc == 0) cwbuf[wid * 64 + m * 16 + quad * 4 + r] = p;
            }
        __syncthreads();

        if (t < 64) {
            float cw = cb2[0] + cwbuf[t] + cwbuf[64 + t] + cwbuf[128 + t] + cwbuf[192 + t];
            float* o = cwrel + (size_t)(k0 + t) * 3;
            o[0] = cw * sRel[t * 3 + 0];
            o[1] = cw * sRel[t * 3 + 1];
            o[2] = cw * sRel[t * 3 + 2];
        }
    }
}

// ---------------- fused aggregation + node MLP (fp16) ----------------
// last=1: coors path dead; fuse the final linear projection (out = feats@linW+linb)
// via lc-shuffle reduce + cross-wave LDS sum; skip feats/featsh stores.
#define HS 136
__global__ __launch_bounds__(256, 4) void agg_node(
    const int* __restrict__ off, const int* __restrict__ deg,
    const short* __restrict__ m_edge, const float* __restrict__ cwrel,
    const float* __restrict__ coors_in, float* __restrict__ coors_out,
    float* __restrict__ feats, short* __restrict__ featsh,
    const short* __restrict__ W1f, const float* __restrict__ b1,
    const short* __restrict__ W2f, const float* __restrict__ b2,
    const float* __restrict__ linW, const float* __restrict__ linb,
    float* __restrict__ out, int last)
{
    __shared__ short sh[64 * HS];   // h = [featsh | agg(m)]
    __shared__ short sg[64 * HS];   // silu(h@W1+b1); tail reused as float red[64][4]
    int t = threadIdx.x, lane = t & 63, wid = t >> 6, quad = lane >> 4, lc = lane & 15;
    int n0 = blockIdx.x * 64;

    {
        int row = t >> 2, sub = t & 3;
        const short8* fp = (const short8*)(featsh + (size_t)(n0 + row) * FH);
        *(short8*)(sh + row * HS + sub * 16) = fp[sub * 2];
        *(short8*)(sh + row * HS + sub * 16 + 8) = fp[sub * 2 + 1];
    }
    // k-loop unrolled x4 with split accumulators to overlap L2 load latency
    for (int nn = 0; nn < 16; nn++) {
        int row = wid * 16 + nn;
        int n = n0 + row;
        float sum = 0.f, cv = 0.f;
        if (n < NN) {
            int s = off[n], e = s + deg[n];
            float s0 = 0.f, s1 = 0.f, s2 = 0.f, s3 = 0.f;
            int k = s;
            for (; k + 3 < e; k += 4) {
                s0 += h2f(m_edge[(size_t)k * FH + lane]);
                s1 += h2f(m_edge[(size_t)(k + 1) * FH + lane]);
                s2 += h2f(m_edge[(size_t)(k + 2) * FH + lane]);
                s3 += h2f(m_edge[(size_t)(k + 3) * FH + lane]);
                if (!last && lane < 3)
                    cv += (cwrel[(size_t)k * 3 + lane] + cwrel[(size_t)(k + 1) * 3 + lane])
                        + (cwrel[(size_t)(k + 2) * 3 + lane] + cwrel[(size_t)(k + 3) * 3 + lane]);
            }
            for (; k < e; k++) {
                s0 += h2f(m_edge[(size_t)k * FH + lane]);
                if (!last && lane < 3) cv += cwrel[(size_t)k * 3 + lane];
            }
            sum = (s0 + s1) + (s2 + s3);
            if (!last && lane < 3) coors_out[n * 3 + lane] = coors_in[n * 3 + lane] + cv;
        }
        sh[row * HS + 64 + lane] = f2h(sum);
    }
    __syncthreads();

    half8 af[4][4];
    #pragma unroll
    for (int m = 0; m < 4; m++)
        #pragma unroll
        for (int kt = 0; kt < 4; kt++)
            af[m][kt] = *(const half8*)(sh + (m * 16 + lc) * HS + kt * 32 + quad * 8);
    #pragma unroll
    for (int i = 0; i < 2; i++) {
        int nt = wid + i * 4;
        float bias = b1[nt * 16 + lc];
        float4v acc[4];
        #pragma unroll
        for (int m = 0; m < 4; m++) acc[m] = (float4v){bias, bias, bias, bias};
        #pragma unroll
        for (int kt = 0; kt < 4; kt++) {
            half8 bh = ((const half8*)(W1f + (size_t)(nt * 4 + kt) * 512))[lane];
            #pragma unroll
            for (int m = 0; m < 4; m++)
                acc[m] = __builtin_amdgcn_mfma_f32_16x16x32_f16(af[m][kt], bh, acc[m], 0, 0, 0);
        }
        #pragma unroll
        for (int m = 0; m < 4; m++)
            #pragma unroll
            for (int r = 0; r < 4; r++)
                sg[(m * 16 + quad * 4 + r) * HS + nt * 16 + lc] = f2h(silu_f(acc[m][r]));
    }
    __syncthreads();

    {
        int nt = wid;
        float bias = b2[nt * 16 + lc];
        float4v acc[4];
        #pragma unroll
        for (int m = 0; m < 4; m++) acc[m] = (float4v){bias, bias, bias, bias};
        #pragma unroll
        for (int kt = 0; kt < 4; kt++) {
            half8 bh = ((const half8*)(W2f + (size_t)(nt * 4 + kt) * 512))[lane];
            #pragma unroll
            for (int m = 0; m < 4; m++) {
                half8 a = *(const half8*)(sg + (m * 16 + lc) * HS + kt * 32 + quad * 8);
                acc[m] = __builtin_amdgcn_mfma_f32_16x16x32_f16(a, bh, acc[m], 0, 0, 0);
            }
        }
        if (!last) {
            #pragma unroll
            for (int m = 0; m < 4; m++)
                #pragma unroll
                for (int r = 0; r < 4; r++) {
                    int row = m * 16 + quad * 4 + r;
                    size_t idx = (size_t)(n0 + row) * FH + nt * 16 + lc;
                    float nv = feats[idx] + acc[m][r];   // residual in fp32
                    feats[idx] = nv;
                    featsh[idx] = f2h(nv);
                }
        } else {
            // fused output projection: out[n] = sum_col (feats+acc)[n][col]*linW[col] + linb
            float lw = linW[nt * 16 + lc];
            float v[4][4];
            #pragma unroll
            for (int m = 0; m < 4; m++)
                #pragma unroll
                for (int r = 0; r < 4; r++) {
                    int row = m * 16 + quad * 4 + r;
                    size_t idx = (size_t)(n0 + row) * FH + nt * 16 + lc;
                    v[m][r] = (feats[idx] + acc[m][r]) * lw;
                }
            __syncthreads();   // all sg A-operand reads complete before overlay
            float* red = (float*)sg;   // [64 rows][4 wid]
            #pragma unroll
            for (int m = 0; m < 4; m++)
                #pragma unroll
                for (int r = 0; r < 4; r++) {
                    float p = v[m][r];
                    p += __shfl_xor(p, 1);
                    p += __shfl_xor(p, 2);
                    p += __shfl_xor(p, 4);
                    p += __shfl_xor(p, 8);
                    if (lc == 0) red[(m * 16 + quad * 4 + r) * 4 + wid] = p;
                }
            __syncthreads();
            if (t < 64) {
                int n = n0 + t;
                if (n < NN)
                    out[n] = (red[t * 4 + 0] + red[t * 4 + 1])
                           + (red[t * 4 + 2] + red[t * 4 + 3]) + linb[0];
            }
        }
    }
}

extern "C" void kernel_launch(void* const* d_in, const int* in_sizes, int n_in,
                              void* d_out, int out_size, void* d_ws, size_t ws_size,
                              hipStream_t stream) {
    const float* x      = (const float*)d_in[0];
    const float* pos    = (const float*)d_in[1];
    const int*   ei     = (const int*)d_in[2];
    const float* eattr  = (const float*)d_in[3];
    const float* embedW = (const float*)d_in[4];
    const float* embedb = (const float*)d_in[5];
    const float* eW1    = (const float*)d_in[6];
    const float* eb1    = (const float*)d_in[7];
    const float* eW2    = (const float*)d_in[8];
    const float* eb2    = (const float*)d_in[9];
    const float* cW1    = (const float*)d_in[10];
    const float* cb1    = (const float*)d_in[11];
    const float* cW2    = (const float*)d_in[12];
    const float* cb2    = (const float*)d_in[13];
    const float* nW1    = (const float*)d_in[14];
    const float* nb1    = (const float*)d_in[15];
    const float* nW2    = (const float*)d_in[16];
    const float* nb2    = (const float*)d_in[17];
    const float* linW   = (const float*)d_in[18];
    const float* linb   = (const float*)d_in[19];
    float* out = (float*)d_out;

    char* wp = (char*)d_ws;
    auto alloc = [&](size_t bytes) { void* p = wp; wp += (bytes + 255) & ~(size_t)255; return p; };

    const int W1F_L  = 17 * 5 * 512;
    const int W2F_L  = 4 * 9 * 512;
    const int CW1F_L = 16 * 2 * 512;
    const int NW1F_L = 8 * 4 * 512;
    const int NW2F_L = 4 * 4 * 512;

    float* feats  = (float*)alloc((size_t)NNP * FH * 4);
    short* featsh = (short*)alloc((size_t)NNP * FH * 2);
    float* cA     = (float*)alloc((size_t)NN * 3 * 4);
    float* cB     = (float*)alloc((size_t)NN * 3 * 4);
    short* W1f    = (short*)alloc((size_t)3 * W1F_L * 2);
    short* W2f    = (short*)alloc((size_t)3 * W2F_L * 2);
    short* cW1f   = (short*)alloc((size_t)3 * CW1F_L * 2);
    short* nW1f   = (short*)alloc((size_t)3 * NW1F_L * 2);
    short* nW2f   = (short*)alloc((size_t)3 * NW2F_L * 2);
    float* b1p    = (float*)alloc((size_t)3 * 272 * 4);
    int*   deg    = (int*)alloc((size_t)(NN + 1) * 4);   // deg[NN] = global cursor
    int*   off    = (int*)alloc((size_t)NN * 4);
    int*   cursor = (int*)alloc((size_t)NN * 4);
    int*   erow   = (int*)alloc((size_t)NE * 4);
    int*   ecol   = (int*)alloc((size_t)NE * 4);
    float* eattrp = (float*)alloc((size_t)NE * 4);
    short* m_edge = (short*)alloc((size_t)NE * FH * 2);
    float* cwrel  = (float*)alloc((size_t)NE * 3 * 4);
    int* gcount = deg + NN;

    // prep: weight frags + b1 pad + deg zeroing (359553 work items)
    prep_all<<<(359553 + 255) / 256, 256, 0, stream>>>(
        eW1, eW2, cW1, nW1, nW2, eb1,
        W1f, W2f, cW1f, nW1f, nW2f, b1p, deg);

    hist_kernel<<<(NE + 255) / 256, 256, 0, stream>>>(ei, deg);
    alloc_kernel<<<(NN + 255) / 256, 256, 0, stream>>>(deg, off, cursor, gcount);
    fill_kernel<<<(NE + 255) / 256, 256, 0, stream>>>(ei, eattr, cursor, erow, ecol, eattrp);

    embed_kernel<<<(NN * FH + 255) / 256, 256, 0, stream>>>(x, embedW, embedb, pos, feats, featsh, cA);

    float* ccur = cA;
    float* cnext = cB;
    for (int l = 0; l < 3; l++) {
        int last = (l == 2);
        edge_fused<<<8 * CHUNK, 256, 0, stream>>>(
            erow, ecol, eattrp, featsh, ccur,
            W1f + (size_t)l * W1F_L, b1p + l * 272,
            W2f + (size_t)l * W2F_L, eb2 + l * 64,
            cW1f + (size_t)l * CW1F_L, cb1 + l * 256,
            cW2 + l * 256, cb2 + l,
            m_edge, cwrel, last ? 0 : 1);
        agg_node<<<NNP / 64, 256, 0, stream>>>(
            off, deg, m_edge, cwrel, ccur, cnext, feats, featsh,
            nW1f + (size_t)l * NW1F_L, nb1 + l * 128,
            nW2f + (size_t)l * NW2F_L, nb2 + l * 64,
            linW, linb, out, last);
        float* tmp = ccur; ccur = cnext; cnext = tmp;
    }
}